// Round 2
// baseline (457.732 us; speedup 1.0000x reference)
//
#include <hip/hip_runtime.h>
#include <hip/hip_bf16.h>
#include <math.h>

#define N_TOK 4096
#define DM 512
#define FDIM 128
#define G 8
#define FG 16
#define DH 128
#define DE 256
#define ES 4
#define E_EXP 32
#define LN_EPS 1e-5f
#define BT 32   // expert token tile (MFMA)

typedef __attribute__((ext_vector_type(8))) short bf16x8;  // 8 bf16 = 4 VGPRs
typedef __attribute__((ext_vector_type(4))) float f32x4;

#define MFMA16(a, b, c) __builtin_amdgcn_mfma_f32_16x16x32_bf16((a), (b), (c), 0, 0, 0)

// tiled split3 fragment layout: [panel p = n/16][kb = col/32][split 0..2][lane 0..63][8 shorts]
// lane encodes (colsub = (lane>>4)*8, token-low = lane&15). Panel stride = 6144 shorts (12 KB).
#define PSTRIDE 6144

__device__ __forceinline__ float gelu_t(float x) {
    const float c = 0.7978845608028654f; // sqrt(2/pi)
    float x3 = x * x * x;
    return 0.5f * x * (1.0f + tanhf(c * (x + 0.044715f * x3)));
}

__device__ __forceinline__ short f2bf(float f) {
    __hip_bfloat16 h = __float2bfloat16(f);
    return *reinterpret_cast<short*>(&h);
}
__device__ __forceinline__ float bf2f(short s) {
    __hip_bfloat16 h = *reinterpret_cast<__hip_bfloat16*>(&s);
    return __bfloat162float(h);
}
// exact 3-way split: x == bf2f(h)+bf2f(m)+bf2f(l) bit-exactly for fp32 x
__device__ __forceinline__ void split3(float x, short& h, short& m, short& l) {
    h = f2bf(x);
    float r = x - bf2f(h);   // exact in fp32
    m = f2bf(r);
    float r2 = r - bf2f(m);  // exact; <=6 significant bits remain
    l = f2bf(r2);            // exact
}

// ---------------- fused pre-pass: weight conversion jobs + LN(hidden) ----------------
struct ConvJob { const float* src; short* dh; short* dm; short* dl;
                 int KB, NB, Kreal, plain, blk0; };
struct ConvJobs { ConvJob j[10]; };

__global__ void k_pre(ConvJobs J, int nconv,
                      const float* __restrict__ hidden,
                      const float* __restrict__ pg, const float* __restrict__ pb,
                      const float* __restrict__ rg, const float* __restrict__ rb,
                      __hip_bfloat16* __restrict__ h_normb, float* __restrict__ hL) {
    int b = blockIdx.x;
    if (b >= nconv) {
        // -------- LN of hidden: pre_ln -> h_norm (bf16) and rh_ln -> hL (fp32) --------
        int n = b - nconv;
        int j = threadIdx.x; // 0..255
        const float* x = hidden + (size_t)n * DM;
        float v0 = x[j], v1 = x[j + 256];
        float s = v0 + v1, q = v0 * v0 + v1 * v1;
#pragma unroll
        for (int o = 32; o; o >>= 1) { s += __shfl_down(s, o); q += __shfl_down(q, o); }
        __shared__ float red[8];
        int w = j >> 6;
        if ((j & 63) == 0) { red[w] = s; red[4 + w] = q; }
        __syncthreads();
        float sum = red[0] + red[1] + red[2] + red[3];
        float sq  = red[4] + red[5] + red[6] + red[7];
        float m = sum * (1.0f / DM);
        float var = sq * (1.0f / DM) - m * m;
        float rs = rsqrtf(var + LN_EPS);
        float t0 = (v0 - m) * rs, t1 = (v1 - m) * rs;
        size_t base = (size_t)n * DM;
        h_normb[base + j]       = __float2bfloat16(t0 * pg[j]       + pb[j]);
        h_normb[base + j + 256] = __float2bfloat16(t1 * pg[j + 256] + pb[j + 256]);
        hL[base + j]           = t0 * rg[j]       + rb[j];
        hL[base + j + 256]     = t1 * rg[j + 256] + rb[j + 256];
        return;
    }
    // -------- weight conversion: plain bf16 or 3-way split, K zero-pad --------
    int ji = 0;
#pragma unroll
    for (int i = 1; i < 10; i++) if (b >= J.j[i].blk0) ji = i;
    const ConvJob jb = J.j[ji];
    int rel = b - jb.blk0;
    int mat = rel / jb.KB, kb = rel % jb.KB;
    int ncols = jb.NB * 16;
    const float* s = jb.src + (size_t)mat * jb.Kreal * ncols;
    size_t dbase = ((size_t)mat * jb.KB + kb) * jb.NB * 512;
    for (int p = threadIdx.x; p < jb.NB * 64; p += 256) {
        int nb = p >> 6, lane = p & 63;
        int row0 = kb * 32 + ((lane >> 4) << 3);
        int col = nb * 16 + (lane & 15);
        if (jb.plain) {
            union { short sh[8]; uint4 v; } t;
#pragma unroll
            for (int j = 0; j < 8; j++) {
                float x = (row0 + j < jb.Kreal) ? s[(size_t)(row0 + j) * ncols + col] : 0.f;
                t.sh[j] = f2bf(x);
            }
            *(uint4*)&jb.dh[dbase + (size_t)p * 8] = t.v;
        } else {
            union { short sh[8]; uint4 v; } hi, mi, lo;
#pragma unroll
            for (int j = 0; j < 8; j++) {
                float x = (row0 + j < jb.Kreal) ? s[(size_t)(row0 + j) * ncols + col] : 0.f;
                split3(x, hi.sh[j], mi.sh[j], lo.sh[j]);
            }
            *(uint4*)&jb.dh[dbase + (size_t)p * 8] = hi.v;
            *(uint4*)&jb.dm[dbase + (size_t)p * 8] = mi.v;
            *(uint4*)&jb.dl[dbase + (size_t)p * 8] = lo.v;
        }
    }
}

// ---- shared epilogue: split3 outputs -> LDS restage -> tiled split3 fragments in global ----
// Values written at [row][col] of A{h,m,l}[32][136]; copied as 24 x 1KB lane-major fragments.
__device__ __forceinline__ void emit_split_tiles(
        int tid, short (*Ah)[136], short (*Am)[136], short (*Al)[136],
        short* __restrict__ Yt, size_t panel0 /* global panel index of row 0 */) {
    int lane_ = tid & 63, w = tid >> 6;   // 4 waves
#pragma unroll
    for (int j = 0; j < 6; j++) {
        int combo = w * 6 + j;            // 0..23 = split(3) x t16(2) x kb(4)
        int split = combo >> 3;
        int rem = combo & 7; int t16 = rem >> 2, kb = rem & 3;
        const short* sp = (split == 0) ? &Ah[0][0] : (split == 1) ? &Am[0][0] : &Al[0][0];
        uint4 v = *(const uint4*)&sp[(t16 * 16 + (lane_ & 15)) * 136 + kb * 32 + (lane_ >> 4) * 8];
        *(uint4*)&Yt[((panel0 + t16) * 4 + kb) * 1536 + split * 512 + lane_ * 8] = v;
    }
}

// ---------------- 2-layer MLP body via 3-split MFMA: Y = gelu(LN?(X)@W1+b1)@W2+b2 ----------------
template <int KB_TOT, bool DO_LN>
__device__ __forceinline__ void enc2_body(
        int bx, char* smem,
        const float* __restrict__ X,
        const float* __restrict__ lng, const float* __restrict__ lnb,
        const short* __restrict__ W1h, const short* __restrict__ W1m, const short* __restrict__ W1l,
        const float* __restrict__ B1,
        const short* __restrict__ W2h, const short* __restrict__ W2m, const short* __restrict__ W2l,
        const float* __restrict__ B2,
        short* __restrict__ Yt) {
    constexpr int K = KB_TOT * 32;
    const int n0 = bx * 32;
    const int tid = threadIdx.x;
    const int wave = tid >> 6, lane = tid & 63;
    const int quad = lane >> 4, lm = lane & 15;
    const int mt = wave & 1;
    const int ngb = (wave >> 1) * 4;   // 4 n-tiles per wave

    short (*Ah)[136] = (short(*)[136])smem;
    short (*Am)[136] = (short(*)[136])(smem + 8704);
    short (*Al)[136] = (short(*)[136])(smem + 2 * 8704);

    f32x4 acc[4];
#pragma unroll
    for (int i = 0; i < 4; i++) acc[i] = (f32x4)(0.f);

    if (DO_LN) {
        for (int idx = tid; idx < 1024; idx += 256) {
            int row = idx >> 5, c4 = (idx & 31) * 4;
            float4 v = *(const float4*)&X[(size_t)(n0 + row) * K + c4];
            float s = v.x + v.y + v.z + v.w;
            float q = v.x * v.x + v.y * v.y + v.z * v.z + v.w * v.w;
#pragma unroll
            for (int o = 16; o; o >>= 1) { s += __shfl_xor(s, o); q += __shfl_xor(q, o); }
            float mean = s * (1.0f / 128.0f);
            float var = q * (1.0f / 128.0f) - mean * mean;
            float rs = rsqrtf(var + LN_EPS);
            float xv[4] = {(v.x - mean) * rs * lng[c4 + 0] + lnb[c4 + 0],
                           (v.y - mean) * rs * lng[c4 + 1] + lnb[c4 + 1],
                           (v.z - mean) * rs * lng[c4 + 2] + lnb[c4 + 2],
                           (v.w - mean) * rs * lng[c4 + 3] + lnb[c4 + 3]};
#pragma unroll
            for (int j = 0; j < 4; j++) {
                short h, m, l; split3(xv[j], h, m, l);
                Ah[row][c4 + j] = h; Am[row][c4 + j] = m; Al[row][c4 + j] = l;
            }
        }
        __syncthreads();
#pragma unroll
        for (int kb = 0; kb < KB_TOT; kb++) {
            bf16x8 ah = *(const bf16x8*)&Ah[mt * 16 + lm][kb * 32 + quad * 8];
            bf16x8 am = *(const bf16x8*)&Am[mt * 16 + lm][kb * 32 + quad * 8];
            bf16x8 al = *(const bf16x8*)&Al[mt * 16 + lm][kb * 32 + quad * 8];
#pragma unroll
            for (int nt = 0; nt < 4; nt++) {
                size_t bi = (((size_t)kb * 8 + ngb + nt) * 64 + lane) * 8;
                bf16x8 bh = *(const bf16x8*)&W1h[bi];
                bf16x8 bm = *(const bf16x8*)&W1m[bi];
                bf16x8 bl = *(const bf16x8*)&W1l[bi];
                acc[nt] = MFMA16(al, bh, acc[nt]);
                acc[nt] = MFMA16(am, bm, acc[nt]);
                acc[nt] = MFMA16(ah, bl, acc[nt]);
                acc[nt] = MFMA16(am, bh, acc[nt]);
                acc[nt] = MFMA16(ah, bm, acc[nt]);
                acc[nt] = MFMA16(ah, bh, acc[nt]);
            }
        }
    } else {
        for (int kb = 0; kb < KB_TOT; kb++) {
            const float* xs = X + (size_t)(n0 + mt * 16 + lm) * K + kb * 32 + quad * 8;
            float4 x0 = *(const float4*)xs, x1 = *(const float4*)(xs + 4);
            float xv[8] = {x0.x, x0.y, x0.z, x0.w, x1.x, x1.y, x1.z, x1.w};
            bf16x8 ah, am, al;
#pragma unroll
            for (int j = 0; j < 8; j++) {
                short h, m, l; split3(xv[j], h, m, l);
                ah[j] = h; am[j] = m; al[j] = l;
            }
#pragma unroll
            for (int nt = 0; nt < 4; nt++) {
                size_t bi = (((size_t)kb * 8 + ngb + nt) * 64 + lane) * 8;
                bf16x8 bh = *(const bf16x8*)&W1h[bi];
                bf16x8 bm = *(const bf16x8*)&W1m[bi];
                bf16x8 bl = *(const bf16x8*)&W1l[bi];
                acc[nt] = MFMA16(al, bh, acc[nt]);
                acc[nt] = MFMA16(am, bm, acc[nt]);
                acc[nt] = MFMA16(ah, bl, acc[nt]);
                acc[nt] = MFMA16(am, bh, acc[nt]);
                acc[nt] = MFMA16(ah, bm, acc[nt]);
                acc[nt] = MFMA16(ah, bh, acc[nt]);
            }
        }
    }
    __syncthreads();
#pragma unroll
    for (int nt = 0; nt < 4; nt++) {
        int col = (ngb + nt) * 16 + lm;
        float b1 = B1[col];
#pragma unroll
        for (int r = 0; r < 4; r++) {
            int row = mt * 16 + quad * 4 + r;
            short h, m, l; split3(gelu_t(acc[nt][r] + b1), h, m, l);
            Ah[row][col] = h; Am[row][col] = m; Al[row][col] = l;
        }
    }
    __syncthreads();
    f32x4 acc2[4];
#pragma unroll
    for (int i = 0; i < 4; i++) acc2[i] = (f32x4)(0.f);
#pragma unroll
    for (int kb = 0; kb < 4; kb++) {
        bf16x8 ah = *(const bf16x8*)&Ah[mt * 16 + lm][kb * 32 + quad * 8];
        bf16x8 am = *(const bf16x8*)&Am[mt * 16 + lm][kb * 32 + quad * 8];
        bf16x8 al = *(const bf16x8*)&Al[mt * 16 + lm][kb * 32 + quad * 8];
#pragma unroll
        for (int nt = 0; nt < 4; nt++) {
            size_t bi = (((size_t)kb * 8 + ngb + nt) * 64 + lane) * 8;
            bf16x8 bh = *(const bf16x8*)&W2h[bi];
            bf16x8 bm = *(const bf16x8*)&W2m[bi];
            bf16x8 bl = *(const bf16x8*)&W2l[bi];
            acc2[nt] = MFMA16(al, bh, acc2[nt]);
            acc2[nt] = MFMA16(am, bm, acc2[nt]);
            acc2[nt] = MFMA16(ah, bl, acc2[nt]);
            acc2[nt] = MFMA16(am, bh, acc2[nt]);
            acc2[nt] = MFMA16(ah, bm, acc2[nt]);
            acc2[nt] = MFMA16(ah, bh, acc2[nt]);
        }
    }
    // epilogue: split3 outputs into LDS, then coalesced tiled-fragment store
    __syncthreads();   // all waves done reading hidden in Ah/Am/Al
#pragma unroll
    for (int nt = 0; nt < 4; nt++) {
        int col = (ngb + nt) * 16 + lm;
        float b2 = B2[col];
#pragma unroll
        for (int r = 0; r < 4; r++) {
            int row = mt * 16 + quad * 4 + r;
            short h, m, l; split3(acc2[nt][r] + b2, h, m, l);
            Ah[row][col] = h; Am[row][col] = m; Al[row][col] = l;
        }
    }
    __syncthreads();
    emit_split_tiles(tid, Ah, Am, Al, Yt, (size_t)bx * 2);
}

// ---------------- single-group encoder body: one (32-token tile, group) per block ----------------
__device__ __forceinline__ void genc_one(
        int bx, int g, char* smem,
        const float* __restrict__ feat,
        const float* __restrict__ gln_g, const float* __restrict__ gln_b,
        const short* __restrict__ W1h, const short* __restrict__ W1m, const short* __restrict__ W1l,
        const float* __restrict__ gb1,
        const short* __restrict__ W2h, const short* __restrict__ W2m, const short* __restrict__ W2l,
        const float* __restrict__ gb2,
        short* __restrict__ Gs) {
    const int tid = threadIdx.x;
    const int wave = tid >> 6, lane = tid & 63;
    const int quad = lane >> 4, lm = lane & 15;
    const int mt = wave & 1;
    const int ngb = (wave >> 1) * 4;
    const int n0 = bx * 32;

    short (*Ah)[136] = (short(*)[136])smem;
    short (*Am)[136] = (short(*)[136])(smem + 8704);
    short (*Al)[136] = (short(*)[136])(smem + 2 * 8704);

    {
        int t = tid >> 3, sub = tid & 7;
        const float* fr = feat + (size_t)(n0 + t) * FDIM + g * FG;
        float xv[FG];
        float mean = 0.f;
#pragma unroll
        for (int i = 0; i < FG; i++) { xv[i] = fr[i]; mean += xv[i]; }
        mean *= (1.0f / FG);
        float var = 0.f;
#pragma unroll
        for (int i = 0; i < FG; i++) { float d = xv[i] - mean; var += d * d; }
        var *= (1.0f / FG);
        float rs = rsqrtf(var + LN_EPS);
#pragma unroll
        for (int j = 0; j < 2; j++) {
            int i = sub * 2 + j;
            float xn = (xv[i] - mean) * rs * gln_g[g * FG + i] + gln_b[g * FG + i];
            short h, m, l; split3(xn, h, m, l);
            Ah[t][i] = h; Am[t][i] = m; Al[t][i] = l;
            Ah[t][16 + i] = 0; Am[t][16 + i] = 0; Al[t][16 + i] = 0;  // K pad to 32
        }
    }
    __syncthreads();
    f32x4 acc[4];
#pragma unroll
    for (int i = 0; i < 4; i++) acc[i] = (f32x4)(0.f);
    {
        bf16x8 ah = *(const bf16x8*)&Ah[mt * 16 + lm][quad * 8];
        bf16x8 am = *(const bf16x8*)&Am[mt * 16 + lm][quad * 8];
        bf16x8 al = *(const bf16x8*)&Al[mt * 16 + lm][quad * 8];
#pragma unroll
        for (int nt = 0; nt < 4; nt++) {
            size_t bi = (((size_t)g * 8 + ngb + nt) * 64 + lane) * 8;  // KB=1 per mat
            bf16x8 bh = *(const bf16x8*)&W1h[bi];
            bf16x8 bm = *(const bf16x8*)&W1m[bi];
            bf16x8 bl = *(const bf16x8*)&W1l[bi];
            acc[nt] = MFMA16(al, bh, acc[nt]);
            acc[nt] = MFMA16(am, bm, acc[nt]);
            acc[nt] = MFMA16(ah, bl, acc[nt]);
            acc[nt] = MFMA16(am, bh, acc[nt]);
            acc[nt] = MFMA16(ah, bm, acc[nt]);
            acc[nt] = MFMA16(ah, bh, acc[nt]);
        }
    }
    __syncthreads();
#pragma unroll
    for (int nt = 0; nt < 4; nt++) {
        int col = (ngb + nt) * 16 + lm;
        float b1 = gb1[g * DH + col];
#pragma unroll
        for (int r = 0; r < 4; r++) {
            int row = mt * 16 + quad * 4 + r;
            short h, m, l; split3(gelu_t(acc[nt][r] + b1), h, m, l);
            Ah[row][col] = h; Am[row][col] = m; Al[row][col] = l;
        }
    }
    __syncthreads();
    f32x4 acc2[4];
#pragma unroll
    for (int i = 0; i < 4; i++) acc2[i] = (f32x4)(0.f);
#pragma unroll
    for (int kb = 0; kb < 4; kb++) {
        bf16x8 a2h = *(const bf16x8*)&Ah[mt * 16 + lm][kb * 32 + quad * 8];
        bf16x8 a2m = *(const bf16x8*)&Am[mt * 16 + lm][kb * 32 + quad * 8];
        bf16x8 a2l = *(const bf16x8*)&Al[mt * 16 + lm][kb * 32 + quad * 8];
#pragma unroll
        for (int nt = 0; nt < 4; nt++) {
            size_t bi = ((((size_t)g * 4 + kb) * 8 + ngb + nt) * 64 + lane) * 8;
            bf16x8 bh = *(const bf16x8*)&W2h[bi];
            bf16x8 bm = *(const bf16x8*)&W2m[bi];
            bf16x8 bl = *(const bf16x8*)&W2l[bi];
            acc2[nt] = MFMA16(a2l, bh, acc2[nt]);
            acc2[nt] = MFMA16(a2m, bm, acc2[nt]);
            acc2[nt] = MFMA16(a2h, bl, acc2[nt]);
            acc2[nt] = MFMA16(a2m, bh, acc2[nt]);
            acc2[nt] = MFMA16(a2h, bm, acc2[nt]);
            acc2[nt] = MFMA16(a2h, bh, acc2[nt]);
        }
    }
    __syncthreads();   // all waves done reading hidden in Ah/Am/Al
#pragma unroll
    for (int nt = 0; nt < 4; nt++) {
        int col = (ngb + nt) * 16 + lm;
        float b2 = gb2[g * DH + col];
#pragma unroll
        for (int r = 0; r < 4; r++) {
            int row = mt * 16 + quad * 4 + r;
            short h, m, l; split3(acc2[nt][r] + b2, h, m, l);
            Ah[row][col] = h; Am[row][col] = m; Al[row][col] = l;
        }
    }
    __syncthreads();
    emit_split_tiles(tid, Ah, Am, Al, Gs, (size_t)g * 256 + bx * 2);
}

// ---------------- fused encoder launch: rh(128) + sf(128) + genc(1024) blocks ----------------
__global__ __launch_bounds__(256) void k_enc_all(
        const float* __restrict__ hL, const float* __restrict__ feat,
        const float* __restrict__ sf_g, const float* __restrict__ sf_b,
        const float* __restrict__ gln_g, const float* __restrict__ gln_b,
        const short* Brh1H, const short* Brh1M, const short* Brh1L, const float* rh_b1,
        const short* Brh2H, const short* Brh2M, const short* Brh2L, const float* rh_b2,
        const short* Bsf1H, const short* Bsf1M, const short* Bsf1L, const float* sf_b1,
        const short* Bsf2H, const short* Bsf2M, const short* Bsf2L, const float* sf_b2,
        const short* Bgf1H, const short* Bgf1M, const short* Bgf1L, const float* gf_b1,
        const short* Bgf2H, const short* Bgf2M, const short* Bgf2L, const float* gf_b2,
        short* __restrict__ Hs, short* __restrict__ Ss, short* __restrict__ Gs) {
    __shared__ __align__(16) char smem[3 * 8704];   // 25.5 KB -> 6 blocks/CU
    int bid = blockIdx.x;
    if (bid < 128)
        enc2_body<16, false>(bid, smem, hL, nullptr, nullptr,
                             Brh1H, Brh1M, Brh1L, rh_b1, Brh2H, Brh2M, Brh2L, rh_b2, Hs);
    else if (bid < 256)
        enc2_body<4, true>(bid - 128, smem, feat, sf_g, sf_b,
                           Bsf1H, Bsf1M, Bsf1L, sf_b1, Bsf2H, Bsf2M, Bsf2L, sf_b2, Ss);
    else {
        int idx = bid - 256;    // (idx & 7) = group -> XCD affinity for gf weights
        genc_one(idx >> 3, idx & 7, smem, feat, gln_g, gln_b,
                 Bgf1H, Bgf1M, Bgf1L, gf_b1, Bgf2H, Bgf2M, Bgf2L, gf_b2, Gs);
    }
}

// ---------------- MFMA router v6: 64 tokens x 1 group, 8 waves, T14 reg-staged pipeline ----------------
// A fragments pre-split by encoders in tiled layout. Chunks 0-2 (h|s|g): per-thread 6x16B
// global loads issued at the START of the previous chunk's MFMA phase (issue-early), LDS
// ds_write_b128 just after the barrier (write-late) -> __syncthreads' vmcnt(0) drain is free.
// Chunk 3 (h*g): 12 loads issued before chunk-2 compute; bit-exact fp32 reconstruct + split3
// in VALU after chunk-2's MFMAs (separate pipes overlap).
__global__ __launch_bounds__(512, 4) void k_router_mfma(
        const short* __restrict__ Hs, const short* __restrict__ Ss, const short* __restrict__ Gs,
        const short* __restrict__ BpgH, const short* __restrict__ BpgM, const short* __restrict__ BpgL,
        const short* __restrict__ BirH, const short* __restrict__ BirM, const short* __restrict__ BirL,
        const float* __restrict__ pb1, const float* __restrict__ pw2, const float* __restrict__ pb2,
        const float* __restrict__ ib1, const float* __restrict__ iw2, const float* __restrict__ ib2,
        float* __restrict__ glog, float* __restrict__ ilog) {
    const int g = blockIdx.x & 7;       // group -> XCD affinity for B + Gs
    const int bx = blockIdx.x >> 3;     // 64-token tile (0..63)
    const int n0 = bx * 64;
    const int tid = threadIdx.x;
    const int wave = tid >> 6, lane = tid & 63;
    const int quad = lane >> 4, lm = lane & 15;
    const bool is_pg = wave < 4;
    const int nbase = (wave & 3) * 2;   // 2 n-tiles per wave, 4 waves cover 8
    const short* Bh = is_pg ? BpgH : (BirH + (size_t)g * 65536);
    const short* Bm = is_pg ? BpgM : (BirM + (size_t)g * 65536);
    const short* Bl = is_pg ? BpgL : (BirL + (size_t)g * 65536);

    const short* HsB = Hs + (size_t)bx * 4 * PSTRIDE;
    const short* SsB = Ss + (size_t)bx * 4 * PSTRIDE;
    const short* GsB = Gs + ((size_t)g * 256 + bx * 4) * PSTRIDE;

    // LDS: A staging for one 4-kb chunk: [split 3][kbl 4][t16 4][lane 64][8 shorts] = 48 KB.
    // Epilogue (2 x 32x129 fp32 = 33 KB) aliases it after the K-loop.
    __shared__ __align__(16) char smem[49152];

    // per-thread staging offsets: 6 slots lin = it*512+tid over (split,kbl,t16,lane);
    // LDS byte off = lin*16 (linear), global short off = tiled-layout address.
    int goff[6];
#pragma unroll
    for (int it = 0; it < 6; it++) {
        int lin = it * 512 + tid;
        int split = lin >> 10, rem = lin & 1023;
        int kbl = rem >> 8, t16 = (rem >> 6) & 3, ln = rem & 63;
        goff[it] = t16 * PSTRIDE + kbl * 1536 + split * 512 + ln * 8;
    }
    // ch3 reconstruction offsets: 2 product-slots slot = t*512+tid over (kbl,t16,lane)
    int roff[2], woff[2];
#pragma unroll
    for (int t = 0; t < 2; t++) {
        int slot = t * 512 + tid;
        int kbl = slot >> 8, t16 = (slot >> 6) & 3, ln = slot & 63;
        roff[t] = t16 * PSTRIDE + kbl * 1536 + ln * 8;
        woff[t] = kbl * 4096 + t16 * 1024 + ln * 16;
    }

    f32x4 acc[4][2];
#pragma unroll
    for (int mt = 0; mt < 4; mt++)
#pragma unroll
        for (int nt = 0; nt < 2; nt++) acc[mt][nt] = (f32x4)(0.f);

    bf16x8 R[6];       // next chunk's fragments (plain chunks)
    bf16x8 R3[2][3];   // chunk-3 reconstructed fragments
#pragma unroll
    for (int it = 0; it < 6; it++) R[it] = *(const bf16x8*)(HsB + goff[it]);

    for (int ch = 0; ch < 4; ch++) {
        __syncthreads();   // previous chunk's LDS reads complete
        if (ch < 3) {
#pragma unroll
            for (int it = 0; it < 6; it++)
                *(bf16x8*)(smem + ((it * 512 + tid) * 16)) = R[it];
        } else {
#pragma unroll
            for (int t = 0; t < 2; t++)
#pragma unroll
                for (int s = 0; s < 3; s++)
                    *(bf16x8*)(smem + s * 16384 + woff[t]) = R3[t][s];
        }
        __syncthreads();   // writes visible
        // issue next chunk's loads NOW -- they complete during this chunk's MFMAs
        bf16x8 Hv[2][3], Gv[2][3];
        if (ch < 2) {
            const short* nb = (ch == 0) ? SsB : GsB;
#pragma unroll
            for (int it = 0; it < 6; it++) R[it] = *(const bf16x8*)(nb + goff[it]);
        } else if (ch == 2) {
#pragma unroll
            for (int t = 0; t < 2; t++)
#pragma unroll
                for (int s = 0; s < 3; s++) {
                    Hv[t][s] = *(const bf16x8*)(HsB + roff[t] + s * 512);
                    Gv[t][s] = *(const bf16x8*)(GsB + roff[t] + s * 512);
                }
        }
        // compute chunk
#pragma unroll
        for (int kbl = 0; kbl < 4; kbl++) {
            int kb = ch * 4 + kbl;
            bf16x8 Ahf[4], Amf[4], Alf[4];
#pragma unroll
            for (int mt = 0; mt < 4; mt++) {
                size_t loff = (size_t)kbl * 4096 + mt * 1024 + (size_t)lane * 16;
                Ahf[mt] = *(const bf16x8*)(smem + loff);
                Amf[mt] = *(const bf16x8*)(smem + 16384 + loff);
                Alf[mt] = *(const bf16x8*)(smem + 32768 + loff);
            }
#pragma unroll
            for (int nt = 0; nt < 2; nt++) {
                int nb = nbase + nt;
                size_t bi = (((size_t)kb * 8 + nb) * 64 + lane) * 8;
                bf16x8 bh = *(const bf16x8*)&Bh[bi];
                bf16x8 bm = *(const bf16x8*)&Bm[bi];
                bf16x8 bl = *(const bf16x8*)&Bl[bi];
#pragma unroll
                for (int mt = 0; mt < 4; mt++) {
                    acc[mt][nt] = MFMA16(Alf[mt], bh, acc[mt][nt]);
                    acc[mt][nt] = MFMA16(Amf[mt], bm, acc[mt][nt]);
                    acc[mt][nt] = MFMA16(Ahf[mt], bl, acc[mt][nt]);
                    acc[mt][nt] = MFMA16(Amf[mt], bh, acc[mt][nt]);
                    acc[mt][nt] = MFMA16(Ahf[mt], bm, acc[mt][nt]);
                    acc[mt][nt] = MFMA16(Ahf[mt], bh, acc[mt][nt]);
                }
            }
        }
        if (ch == 2) {
            // reconstruct h*g bit-exactly from splits; VALU overlaps MFMA tail
#pragma unroll
            for (int t = 0; t < 2; t++) {
                bf16x8 oa, ob, oc;
#pragma unroll
                for (int j = 0; j < 8; j++) {
                    float hv = bf2f(Hv[t][0][j]) + bf2f(Hv[t][1][j]) + bf2f(Hv[t][2][j]);
                    float gv = bf2f(Gv[t][0][j]) + bf2f(Gv[t][1][j]) + bf2f(Gv[t][2][j]);
                    short a_, b_, c_; split3(hv * gv, a_, b_, c_);
                    oa[j] = a_; ob[j] = b_; oc[j] = c_;
                }
                R3[t][0] = oa; R3[t][1] = ob; R3[t][2] = oc;
            }
        }
    }

    // epilogue: two 32-row halves reusing staging LDS (ph 32x129 + ih 32x129 = 33 KB)
    float (*ph)[129] = (float(*)[129])smem;
    float (*ih)[129] = (float(*)[129])(smem + 32 * 129 * 4);
    for (int h = 0; h < 2; h++) {
        __syncthreads();   // h=0: K-loop LDS reads done; h=1: prev half's logit reads done
#pragma unroll
        for (int mi = 0; mi < 2; mi++) {
            int mt = 2 * h + mi;
#pragma unroll
            for (int nt = 0; nt < 2; nt++) {
                int col = (nbase + nt) * 16 + lm;
                float b1 = is_pg ? pb1[col] : ib1[g * DH + col];
                float* dst = is_pg ? &ph[0][0] : &ih[0][0];
#pragma unroll
                for (int r = 0; r < 4; r++) {
                    int row = mi * 16 + quad * 4 + r;
                    dst[row * 129 + col] = gelu_t(acc[mt][nt][r] + b1);
                }
            }
        }
        __syncthreads();
        if (tid < 128) {
            // glog dot: 4 lanes per token, 32 i's each, pair-reduce
            int t = tid >> 2, q = tid & 3;
            float s = 0.f;
            for (int i = q * 32; i < q * 32 + 32; i++) s += ph[t][i] * pw2[i];
            s += __shfl_xor(s, 1);
            s += __shfl_xor(s, 2);
            if (q == 0) glog[(size_t)(n0 + h * 32 + t) * G + g] = s + pb2[0]; // TEMP = 1.0
        } else if (tid < 384) {
            // ilog dot: 2 lanes per (token, e), 64 i's each
            int t2 = tid - 128;
            int t = t2 >> 3, e = (t2 >> 1) & 3, half = t2 & 1;
            const float* wv = iw2 + (size_t)g * DH * ES;
            float s = 0.f;
            for (int i = half * 64; i < half * 64 + 64; i++) s += ih[t][i] * wv[i * ES + e];
            s += __shfl_xor(s, 1);
            if (half == 0) ilog[((size_t)(n0 + h * 32 + t) * G + g) * ES + e] = s + ib2[g * ES + e];
        }
    }
}

// ---------------- top-k softmax + dispatch to per-expert lists ----------------
__global__ void k_topk(const float* __restrict__ glog, const float* __restrict__ ilog,
                       int* __restrict__ cnt, int* __restrict__ toks, float* __restrict__ wgts) {
    int n = blockIdx.x * blockDim.x + threadIdx.x;
    if (n >= N_TOK) return;
    float gl[G];
#pragma unroll
    for (int g = 0; g < G; g++) gl[g] = glog[(size_t)n * G + g];
    int i1 = 0; float v1 = gl[0];
#pragma unroll
    for (int g = 1; g < G; g++) if (gl[g] > v1) { v1 = gl[g]; i1 = g; }
    int i2 = -1; float v2 = -1e30f;
#pragma unroll
    for (int g = 0; g < G; g++) if (g != i1 && gl[g] > v2) { v2 = gl[g]; i2 = g; }
    float eg = expf(v2 - v1);
    float den = 1.0f / (1.0f + eg);
    float gw_sel[2] = { den, eg * den };
    int g_sel[2] = { i1, i2 };
#pragma unroll
    for (int s = 0; s < 2; s++) {
        int g = g_sel[s]; float gw = gw_sel[s];
        float il[ES];
#pragma unroll
        for (int e = 0; e < ES; e++) il[e] = ilog[((size_t)n * G + g) * ES + e];
        int j1 = 0; float u1 = il[0];
#pragma unroll
        for (int e = 1; e < ES; e++) if (il[e] > u1) { u1 = il[e]; j1 = e; }
        int j2 = -1; float u2 = -1e30f;
#pragma unroll
        for (int e = 0; e < ES; e++) if (e != j1 && il[e] > u2) { u2 = il[e]; j2 = e; }
        float ei = expf(u2 - u1);
        float d2 = 1.0f / (1.0f + ei);
        int ex1 = g * ES + j1, ex2 = g * ES + j2;
        int p1 = atomicAdd(&cnt[ex1], 1);
        toks[(size_t)ex1 * N_TOK + p1] = n * 4 + s * 2;     wgts[(size_t)ex1 * N_TOK + p1] = gw * d2;
        int p2 = atomicAdd(&cnt[ex2], 1);
        toks[(size_t)ex2 * N_TOK + p2] = n * 4 + s * 2 + 1; wgts[(size_t)ex2 * N_TOK + p2] = gw * ei * d2;
    }
}

// ---------------- sparse expert MLPs via bf16 MFMA; XCD-swizzled; es aliases hs (33KB LDS) ----------------
__global__ __launch_bounds__(512) void k_expert_mfma(
        const __hip_bfloat16* __restrict__ h_normb,
        const short* __restrict__ wB1, const float* __restrict__ eb1,
        const short* __restrict__ wB2, const float* __restrict__ eb2,
        const int* __restrict__ cnt, const int* __restrict__ toks,
        const float* __restrict__ wgts, float* __restrict__ part) {
    const int e = blockIdx.x & 31;
    const int slot = blockIdx.x >> 5;
    const int c = cnt[e];
    const int start = slot * BT;
    if (start >= c) return;
    const int m = min(BT, c - start);

    __shared__ short hs[BT][520];                   // 33.3 KB; es aliases (dead after phase 1)
    short (*es)[264] = (short(*)[264])&hs[0][0];    // 16.9 KB
    __shared__ int   tok_s[BT];
    __shared__ float w_s[BT];

    const int tid = threadIdx.x;
    if (tid < BT) {
        bool ok = tid < m;
        tok_s[tid] = ok ? toks[(size_t)e * N_TOK + start + tid] : 0;
        w_s[tid]   = ok ? wgts[(size_t)e * N_TOK + start + tid] : 0.f;
    }
    __syncthreads();
    for (int idx = tid; idx < BT * 64; idx += 512) {
        int t = idx >> 6, ch = idx & 63;
        uint4 v = make_uint4(0, 0, 0, 0);
        if (t < m) v = *((const uint4*)(h_normb + (size_t)(tok_s[t] >> 2) * DM) + ch);
        *(uint4*)&hs[t][ch * 8] = v;
    }
    __syncthreads();

    const int wave = tid >> 6, lane = tid & 63;
    const int quad = lane >> 4, lm = lane & 15;

    // ---- phase 1: acc = hs @ W1 (reads hs) ----
    const int ng = wave * 2;
    f32x4 acc1[2][2];
#pragma unroll
    for (int a = 0; a < 2; a++)
#pragma unroll
        for (int b = 0; b < 2; b++) acc1[a][b] = (f32x4)(0.f);
    {
        const short* w1e = wB1 + (size_t)e * DM * DE;
        for (int kb = 0; kb < 16; kb++) {
            bf16x8 a0 = *(const bf16x8*)&hs[lm][kb * 32 + quad * 8];
            bf16x8 a1 = *(const bf16x8*)&hs[16 + lm][kb * 32 + quad * 8];
            const short* wp = w1e + ((size_t)kb * 16 + ng) * 512 + lane * 8;
#pragma unroll
            for (int nt = 0; nt < 2; nt++) {
                bf16x8 b = *(const bf16x8*)(wp + nt * 512);
                acc1[0][nt] = MFMA16(a0, b, acc1[0][nt]);
                acc1[1][nt] = MFMA16(a1, b, acc1[1][nt]);
            }
        }
    }
    __syncthreads();   // all waves done reading hs before es overwrite
#pragma unroll
    for (int nt = 0; nt < 2; nt++) {
        int col = (ng + nt) * 16 + lm;
        float b1 = eb1[e * DE + col];
#pragma unroll
        for (int mt = 0; mt < 2; mt++)
#pragma unroll
        for (int r = 0; r < 4; r++) {
            int row = mt * 16 + quad * 4 + r;
            es[row][col] = f2bf(gelu_t(acc1[mt][nt][r] + b1));
        }
    }
    __syncthreads();

    // ---- phase 2: part[tok] = w * (es @ W2 + b2) ----
    {
        const int ng2 = wave * 4;
        f32x4 acc[2][4];
#pragma unroll
        for (int a = 0; a < 2; a++)
#pragma unroll
            for (int b = 0; b < 4; b++) acc[a][b] = (f32x4)(0.f);
        const short* w2e = wB2 + (size_t)e * DE * DM;
        for (int kb = 0; kb < 8; kb++) {
            bf16x8 a0 = *(const bf16x8*)&es[lm][kb * 32 + quad * 8];
            bf16x8 a1 = *(const bf16x8*)&es[16 + lm][kb * 32 + quad * 8];
            const short* wp = w2e + ((size_t)kb * 32 + ng2) * 512 + lane * 8;
#pragma unroll
            for (int nt = 0; nt < 4; nt++) {
                bf16x8 b = *(const bf16x8*)(wp + nt * 512);
                acc[0][nt] = MFMA16(a0, b, acc[0][nt]);
                acc[1][nt] = MFMA16(a1, b, acc[1][nt]);
            }
        }
        const float* b2 = eb2 + (size_t)e * DM;
#pragma unroll
        for (int mt = 0; mt < 2; mt++)
#pragma unroll
        for (int r = 0; r < 4; r++) {
            int row = mt * 16 + quad * 4 + r;
            if (row < m) {
                float w = w_s[row];
                float* prow = part + (size_t)tok_s[row] * DM;
#pragma unroll
                for (int nt = 0; nt < 4; nt++) {
                    int col = (ng2 + nt) * 16 + lm;
                    prow[col] = w * (acc[mt][nt][r] + b2[col]);
                }
            }
        }
    }
}

// ---------------- final reduce: out[n] = sum_s part[n*4+s] ----------------
__global__ void k_reduce(const float* __restrict__ part, float* __restrict__ out) {
    int n = blockIdx.x;
    int j = threadIdx.x; // 0..127
    const float4* p = (const float4*)(part + (size_t)n * 4 * DM);
    float4 a = p[j], b = p[128 + j], c = p[256 + j], d = p[384 + j];
    float4 r = make_float4(a.x + b.x + c.x + d.x, a.y + b.y + c.y + d.y,
                           a.z + b.z + c.z + d.z, a.w + b.w + c.w + d.w);
    ((float4*)(out + (size_t)n * DM))[j] = r;
}

extern "C" void kernel_launch(void* const* d_in, const int* in_sizes, int n_in,
                              void* d_out, int out_size, void* d_ws, size_t ws_size,
                              hipStream_t stream) {
    const float* hidden  = (const float*)d_in[0];
    const float* feat    = (const float*)d_in[1];
    const float* pre_g   = (const float*)d_in[2];
    const float* pre_b   = (const float*)d_in[3];
    const float* rh_g    = (const float*)d_in[4];
    const float* rh_b    = (const float*)d_in[5];
    const float* rh_w1   = (const float*)d_in[6];
    const float* rh_b1   = (const float*)d_in[7];
    const float* rh_w2   = (const float*)d_in[8];
    const float* rh_b2   = (const float*)d_in[9];
    const float* sf_g    = (const float*)d_in[10];
    const float* sf_b    = (const float*)d_in[11];
    const float* sf_w1   = (const float*)d_in[12];
    const float* sf_b1   = (const float*)d_in[13];
    const float* sf_w2   = (const float*)d_in[14];
    const float* sf_b2   = (const float*)d_in[15];
    const float* gln_g   = (const float*)d_in[16];
    const float* gln_b   = (const float*)d_in[17];
    const float* gf_w1   = (const float*)d_in[18];
    const float* gf_b1   = (const float*)d_in[19];
    const float* gf_w2   = (const float*)d_in[20];
    const float* gf_b2   = (const float*)d_in[21];
    const float* pgs_w1  = (const float*)d_in[22];
    const float* pgs_b1  = (const float*)d_in[23];
    const float* pgs_w2  = (const float*)d_in[24];
    const float* pgs_b2  = (const float*)d_in[25];
    const float* ir_w1   = (const float*)d_in[26];
    const float* ir_b1   = (const float*)d_in[27];
    const float* ir_w2   = (const float*)d_in[28];
    const float* ir_b2   = (const float*)d_in[29];
    const float* ex_w1   = (const float*)d_in[30];
    const float* ex_b1   = (const float*)d_in[31];
    const float* ex_w2   = (const float*)d_in[32];
    const float* ex_b2   = (const float*)d_in[33];
    float* out = (float*)d_out;

    // workspace carving (256B-aligned)
    char* w = (char*)d_ws;
    auto alloc = [&](size_t bytes) { void* r = (void*)w; w += (bytes + 255) & ~(size_t)255; return r; };
    __hip_bfloat16* h_normb = (__hip_bfloat16*)alloc((size_t)N_TOK * DM * 2);
    short* Hs    = (short*)alloc((size_t)256 * PSTRIDE * 2);   // 3 MB tiled split3 h_enc
    short* Ss    = (short*)alloc((size_t)256 * PSTRIDE * 2);   // 3 MB tiled split3 s_enc
    float* glog  = (float*)alloc((size_t)N_TOK * G * 4);
    float* ilog  = (float*)alloc((size_t)N_TOK * G * ES * 4);
    float* wgts  = (float*)alloc((size_t)E_EXP * N_TOK * 4);
    short* wB1   = (short*)alloc((size_t)E_EXP * DM * DE * 2);
    short* wB2   = (short*)alloc((size_t)E_EXP * DE * DM * 2);
    short* BpgH  = (short*)alloc((size_t)16 * 8 * 512 * 2);
    short* BpgM  = (short*)alloc((size_t)16 * 8 * 512 * 2);
    short* BpgL  = (short*)alloc((size_t)16 * 8 * 512 * 2);
    short* BirH  = (short*)alloc((size_t)G * 16 * 8 * 512 * 2);
    short* BirM  = (short*)alloc((size_t)G * 16 * 8 * 512 * 2);
    short* BirL  = (short*)alloc((size_t)G * 16 * 8 * 512 * 2);
    short* Brh1H = (short*)alloc((size_t)16 * 8 * 512 * 2);
    short* Brh1M = (short*)alloc((size_t)16 * 8 * 512 * 2);
    short* Brh1L = (short*)alloc((size_t)16 * 8 * 512 * 2);
    short* Brh2H = (short*)alloc((size_t)4 * 8 * 512 * 2);
    short* Brh2M = (short*)alloc((size_t)4 * 8 * 512 * 2);
    short* Brh2L = (short*)alloc((size_t)4 * 8 * 512 * 2);
    short* Bsf1H = (short*)alloc((size_t)4 * 8 * 512 * 2);
    short* Bsf1M = (short*)alloc((size_t)4 * 8 * 512 * 2);
    short* Bsf1L = (short*)alloc((size_t)4 * 8 * 512 * 2);
    short* Bsf2H = (short*)alloc((size_t)4 * 8 * 512 * 2);
    short* Bsf2M = (short*)alloc((size_t)4 * 8 * 512 * 2);
    short* Bsf2L = (short*)alloc((size_t)4 * 8 * 512 * 2);
    short* Bgf1H = (short*)alloc((size_t)G * 1 * 8 * 512 * 2);
    short* Bgf1M = (short*)alloc((size_t)G * 1 * 8 * 512 * 2);
    short* Bgf1L = (short*)alloc((size_t)G * 1 * 8 * 512 * 2);
    short* Bgf2H = (short*)alloc((size_t)G * 4 * 8 * 512 * 2);
    short* Bgf2M = (short*)alloc((size_t)G * 4 * 8 * 512 * 2);
    short* Bgf2L = (short*)alloc((size_t)G * 4 * 8 * 512 * 2);
    int* cnt     = (int*)alloc(E_EXP * 4);
    int* toks    = (int*)alloc((size_t)E_EXP * N_TOK * 4);
    // union region (disjoint live ranges, stream-ordered):
    //   hL   [k_pre -> k_enc_all]           8.4 MB  (front of uni)
    //   Gs   [k_enc_all -> k_router_mfma]  24.0 MB  (uni + 8.4 MB)
    //   part [k_expert_mfma -> k_reduce]   33.6 MB  (all of uni)
    char* uni   = (char*)alloc((size_t)N_TOK * 4 * DM * 4); // 33.6 MB = max
    float* hL   = (float*)uni;
    short* Gs   = (short*)(uni + (size_t)N_TOK * DM * 4);   // 24 MB tiled split3 g_enc
    float* part = (float*)uni;

    hipMemsetAsync(cnt, 0, E_EXP * sizeof(int), stream);

    // fused pre-pass: 10 weight-conversion jobs + 4096 LN blocks, one launch
    ConvJobs J;
    int b0 = 0;
    auto mkjob = [&](int i, const float* s, short* dh, short* dm, short* dl,
                     int KB, int NB, int Kreal, int plain, int nmat) {
        J.j[i] = ConvJob{s, dh, dm, dl, KB, NB, Kreal, plain, b0};
        b0 += KB * nmat;
    };
    mkjob(0, ex_w1, wB1, nullptr, nullptr, 16, 16, 512, 1, E_EXP);
    mkjob(1, ex_w2, wB2, nullptr, nullptr, 8, 32, 256, 1, E_EXP);
    mkjob(2, pgs_w1, BpgH, BpgM, BpgL, 16, 8, 512, 0, 1);
    mkjob(3, ir_w1, BirH, BirM, BirL, 16, 8, 512, 0, G);
    mkjob(4, rh_w1, Brh1H, Brh1M, Brh1L, 16, 8, 512, 0, 1);
    mkjob(5, rh_w2, Brh2H, Brh2M, Brh2L, 4, 8, 128, 0, 1);
    mkjob(6, sf_w1, Bsf1H, Bsf1M, Bsf1L, 4, 8, 128, 0, 1);
    mkjob(7, sf_w2, Bsf2H, Bsf2M, Bsf2L, 4, 8, 128, 0, 1);
    mkjob(8, gf_w1, Bgf1H, Bgf1M, Bgf1L, 1, 8, 16, 0, G);
    mkjob(9, gf_w2, Bgf2H, Bgf2M, Bgf2L, 4, 8, 128, 0, G);
    k_pre<<<b0 + N_TOK, 256, 0, stream>>>(J, b0, hidden, pre_g, pre_b, rh_g, rh_b, h_normb, hL);

    // fused encoders: rh(128) + sf(128) + per-(tile,group) genc(1024) = 1280 blocks
    k_enc_all<<<256 + (N_TOK / 32) * G, 256, 0, stream>>>(
        hL, feat, sf_g, sf_b, gln_g, gln_b,
        Brh1H, Brh1M, Brh1L, rh_b1, Brh2H, Brh2M, Brh2L, rh_b2,
        Bsf1H, Bsf1M, Bsf1L, sf_b1, Bsf2H, Bsf2M, Bsf2L, sf_b2,
        Bgf1H, Bgf1M, Bgf1L, gf_b1, Bgf2H, Bgf2M, Bgf2L, gf_b2,
        Hs, Ss, Gs);

    // router v6: 64-token tiles, 512 threads, T14 reg-staged pipeline
    k_router_mfma<<<(N_TOK / 64) * G, 512, 0, stream>>>(Hs, Ss, Gs,
                                             BpgH, BpgM, BpgL, BirH, BirM, BirL,
                                             pgs_b1, pgs_w2, pgs_b2, ir_b1, ir_w2, ir_b2,
                                             glog, ilog);

    k_topk<<<N_TOK / 256, 256, 0, stream>>>(glog, ilog, cnt, toks, wgts);
    // XCD-swizzled 1D expert grid: bid = slot*32 + e
    k_expert_mfma<<<(N_TOK / BT) * E_EXP, 512, 0, stream>>>(h_normb, wB1, ex_b1, wB2, ex_b2,
                                                            cnt, toks, wgts, part);
    k_reduce<<<N_TOK, 128, 0, stream>>>(part, out);
}

// Round 3
// 345.591 us; speedup vs baseline: 1.3245x; 1.3245x over previous
//
#include <hip/hip_runtime.h>
#include <hip/hip_bf16.h>
#include <math.h>

#define N_TOK 4096
#define DM 512
#define FDIM 128
#define G 8
#define FG 16
#define DH 128
#define DE 256
#define ES 4
#define E_EXP 32
#define LN_EPS 1e-5f
#define BT 32   // expert token tile (MFMA)

typedef __attribute__((ext_vector_type(8))) short bf16x8;  // 8 bf16 = 4 VGPRs
typedef __attribute__((ext_vector_type(4))) float f32x4;

#define MFMA16(a, b, c) __builtin_amdgcn_mfma_f32_16x16x32_bf16((a), (b), (c), 0, 0, 0)

// tiled split3 fragment layout: [panel p = n/16][kb = col/32][split 0..2][lane 0..63][8 shorts]
// lane encodes (colsub = (lane>>4)*8, token-low = lane&15). Panel stride = 6144 shorts (12 KB).
#define PSTRIDE 6144

__device__ __forceinline__ float gelu_t(float x) {
    const float c = 0.7978845608028654f; // sqrt(2/pi)
    float x3 = x * x * x;
    return 0.5f * x * (1.0f + tanhf(c * (x + 0.044715f * x3)));
}

__device__ __forceinline__ short f2bf(float f) {
    __hip_bfloat16 h = __float2bfloat16(f);
    return *reinterpret_cast<short*>(&h);
}
__device__ __forceinline__ float bf2f(short s) {
    __hip_bfloat16 h = *reinterpret_cast<__hip_bfloat16*>(&s);
    return __bfloat162float(h);
}
// exact 3-way split: x == bf2f(h)+bf2f(m)+bf2f(l) bit-exactly for fp32 x
__device__ __forceinline__ void split3(float x, short& h, short& m, short& l) {
    h = f2bf(x);
    float r = x - bf2f(h);   // exact in fp32
    m = f2bf(r);
    float r2 = r - bf2f(m);  // exact; <=6 significant bits remain
    l = f2bf(r2);            // exact
}

// ---------------- fused pre-pass: weight conversion jobs + LN(hidden) ----------------
struct ConvJob { const float* src; short* dh; short* dm; short* dl;
                 int KB, NB, Kreal, plain, blk0; };
struct ConvJobs { ConvJob j[10]; };

__global__ void k_pre(ConvJobs J, int nconv,
                      const float* __restrict__ hidden,
                      const float* __restrict__ pg, const float* __restrict__ pb,
                      const float* __restrict__ rg, const float* __restrict__ rb,
                      __hip_bfloat16* __restrict__ h_normb, float* __restrict__ hL) {
    int b = blockIdx.x;
    if (b >= nconv) {
        // -------- LN of hidden: pre_ln -> h_norm (bf16) and rh_ln -> hL (fp32) --------
        int n = b - nconv;
        int j = threadIdx.x; // 0..255
        const float* x = hidden + (size_t)n * DM;
        float v0 = x[j], v1 = x[j + 256];
        float s = v0 + v1, q = v0 * v0 + v1 * v1;
#pragma unroll
        for (int o = 32; o; o >>= 1) { s += __shfl_down(s, o); q += __shfl_down(q, o); }
        __shared__ float red[8];
        int w = j >> 6;
        if ((j & 63) == 0) { red[w] = s; red[4 + w] = q; }
        __syncthreads();
        float sum = red[0] + red[1] + red[2] + red[3];
        float sq  = red[4] + red[5] + red[6] + red[7];
        float m = sum * (1.0f / DM);
        float var = sq * (1.0f / DM) - m * m;
        float rs = rsqrtf(var + LN_EPS);
        float t0 = (v0 - m) * rs, t1 = (v1 - m) * rs;
        size_t base = (size_t)n * DM;
        h_normb[base + j]       = __float2bfloat16(t0 * pg[j]       + pb[j]);
        h_normb[base + j + 256] = __float2bfloat16(t1 * pg[j + 256] + pb[j + 256]);
        hL[base + j]           = t0 * rg[j]       + rb[j];
        hL[base + j + 256]     = t1 * rg[j + 256] + rb[j + 256];
        return;
    }
    // -------- weight conversion: plain bf16 or 3-way split, K zero-pad --------
    int ji = 0;
#pragma unroll
    for (int i = 1; i < 10; i++) if (b >= J.j[i].blk0) ji = i;
    const ConvJob jb = J.j[ji];
    int rel = b - jb.blk0;
    int mat = rel / jb.KB, kb = rel % jb.KB;
    int ncols = jb.NB * 16;
    const float* s = jb.src + (size_t)mat * jb.Kreal * ncols;
    size_t dbase = ((size_t)mat * jb.KB + kb) * jb.NB * 512;
    for (int p = threadIdx.x; p < jb.NB * 64; p += 256) {
        int nb = p >> 6, lane = p & 63;
        int row0 = kb * 32 + ((lane >> 4) << 3);
        int col = nb * 16 + (lane & 15);
        if (jb.plain) {
            union { short sh[8]; uint4 v; } t;
#pragma unroll
            for (int j = 0; j < 8; j++) {
                float x = (row0 + j < jb.Kreal) ? s[(size_t)(row0 + j) * ncols + col] : 0.f;
                t.sh[j] = f2bf(x);
            }
            *(uint4*)&jb.dh[dbase + (size_t)p * 8] = t.v;
        } else {
            union { short sh[8]; uint4 v; } hi, mi, lo;
#pragma unroll
            for (int j = 0; j < 8; j++) {
                float x = (row0 + j < jb.Kreal) ? s[(size_t)(row0 + j) * ncols + col] : 0.f;
                split3(x, hi.sh[j], mi.sh[j], lo.sh[j]);
            }
            *(uint4*)&jb.dh[dbase + (size_t)p * 8] = hi.v;
            *(uint4*)&jb.dm[dbase + (size_t)p * 8] = mi.v;
            *(uint4*)&jb.dl[dbase + (size_t)p * 8] = lo.v;
        }
    }
}

// ---- shared epilogue: split3 outputs -> LDS restage -> tiled split3 fragments in global ----
// Values written at [row][col] of A{h,m,l}[32][136]; copied as 24 x 1KB lane-major fragments.
__device__ __forceinline__ void emit_split_tiles(
        int tid, short (*Ah)[136], short (*Am)[136], short (*Al)[136],
        short* __restrict__ Yt, size_t panel0 /* global panel index of row 0 */) {
    int lane_ = tid & 63, w = tid >> 6;   // 4 waves
#pragma unroll
    for (int j = 0; j < 6; j++) {
        int combo = w * 6 + j;            // 0..23 = split(3) x t16(2) x kb(4)
        int split = combo >> 3;
        int rem = combo & 7; int t16 = rem >> 2, kb = rem & 3;
        const short* sp = (split == 0) ? &Ah[0][0] : (split == 1) ? &Am[0][0] : &Al[0][0];
        uint4 v = *(const uint4*)&sp[(t16 * 16 + (lane_ & 15)) * 136 + kb * 32 + (lane_ >> 4) * 8];
        *(uint4*)&Yt[((panel0 + t16) * 4 + kb) * 1536 + split * 512 + lane_ * 8] = v;
    }
}

// ---------------- 2-layer MLP body via 3-split MFMA: Y = gelu(LN?(X)@W1+b1)@W2+b2 ----------------
template <int KB_TOT, bool DO_LN>
__device__ __forceinline__ void enc2_body(
        int bx, char* smem,
        const float* __restrict__ X,
        const float* __restrict__ lng, const float* __restrict__ lnb,
        const short* __restrict__ W1h, const short* __restrict__ W1m, const short* __restrict__ W1l,
        const float* __restrict__ B1,
        const short* __restrict__ W2h, const short* __restrict__ W2m, const short* __restrict__ W2l,
        const float* __restrict__ B2,
        short* __restrict__ Yt) {
    constexpr int K = KB_TOT * 32;
    const int n0 = bx * 32;
    const int tid = threadIdx.x;
    const int wave = tid >> 6, lane = tid & 63;
    const int quad = lane >> 4, lm = lane & 15;
    const int mt = wave & 1;
    const int ngb = (wave >> 1) * 4;   // 4 n-tiles per wave

    short (*Ah)[136] = (short(*)[136])smem;
    short (*Am)[136] = (short(*)[136])(smem + 8704);
    short (*Al)[136] = (short(*)[136])(smem + 2 * 8704);

    f32x4 acc[4];
#pragma unroll
    for (int i = 0; i < 4; i++) acc[i] = (f32x4)(0.f);

    if (DO_LN) {
        for (int idx = tid; idx < 1024; idx += 256) {
            int row = idx >> 5, c4 = (idx & 31) * 4;
            float4 v = *(const float4*)&X[(size_t)(n0 + row) * K + c4];
            float s = v.x + v.y + v.z + v.w;
            float q = v.x * v.x + v.y * v.y + v.z * v.z + v.w * v.w;
#pragma unroll
            for (int o = 16; o; o >>= 1) { s += __shfl_xor(s, o); q += __shfl_xor(q, o); }
            float mean = s * (1.0f / 128.0f);
            float var = q * (1.0f / 128.0f) - mean * mean;
            float rs = rsqrtf(var + LN_EPS);
            float xv[4] = {(v.x - mean) * rs * lng[c4 + 0] + lnb[c4 + 0],
                           (v.y - mean) * rs * lng[c4 + 1] + lnb[c4 + 1],
                           (v.z - mean) * rs * lng[c4 + 2] + lnb[c4 + 2],
                           (v.w - mean) * rs * lng[c4 + 3] + lnb[c4 + 3]};
#pragma unroll
            for (int j = 0; j < 4; j++) {
                short h, m, l; split3(xv[j], h, m, l);
                Ah[row][c4 + j] = h; Am[row][c4 + j] = m; Al[row][c4 + j] = l;
            }
        }
        __syncthreads();
#pragma unroll
        for (int kb = 0; kb < KB_TOT; kb++) {
            bf16x8 ah = *(const bf16x8*)&Ah[mt * 16 + lm][kb * 32 + quad * 8];
            bf16x8 am = *(const bf16x8*)&Am[mt * 16 + lm][kb * 32 + quad * 8];
            bf16x8 al = *(const bf16x8*)&Al[mt * 16 + lm][kb * 32 + quad * 8];
#pragma unroll
            for (int nt = 0; nt < 4; nt++) {
                size_t bi = (((size_t)kb * 8 + ngb + nt) * 64 + lane) * 8;
                bf16x8 bh = *(const bf16x8*)&W1h[bi];
                bf16x8 bm = *(const bf16x8*)&W1m[bi];
                bf16x8 bl = *(const bf16x8*)&W1l[bi];
                acc[nt] = MFMA16(al, bh, acc[nt]);
                acc[nt] = MFMA16(am, bm, acc[nt]);
                acc[nt] = MFMA16(ah, bl, acc[nt]);
                acc[nt] = MFMA16(am, bh, acc[nt]);
                acc[nt] = MFMA16(ah, bm, acc[nt]);
                acc[nt] = MFMA16(ah, bh, acc[nt]);
            }
        }
    } else {
        for (int kb = 0; kb < KB_TOT; kb++) {
            const float* xs = X + (size_t)(n0 + mt * 16 + lm) * K + kb * 32 + quad * 8;
            float4 x0 = *(const float4*)xs, x1 = *(const float4*)(xs + 4);
            float xv[8] = {x0.x, x0.y, x0.z, x0.w, x1.x, x1.y, x1.z, x1.w};
            bf16x8 ah, am, al;
#pragma unroll
            for (int j = 0; j < 8; j++) {
                short h, m, l; split3(xv[j], h, m, l);
                ah[j] = h; am[j] = m; al[j] = l;
            }
#pragma unroll
            for (int nt = 0; nt < 4; nt++) {
                size_t bi = (((size_t)kb * 8 + ngb + nt) * 64 + lane) * 8;
                bf16x8 bh = *(const bf16x8*)&W1h[bi];
                bf16x8 bm = *(const bf16x8*)&W1m[bi];
                bf16x8 bl = *(const bf16x8*)&W1l[bi];
                acc[nt] = MFMA16(al, bh, acc[nt]);
                acc[nt] = MFMA16(am, bm, acc[nt]);
                acc[nt] = MFMA16(ah, bl, acc[nt]);
                acc[nt] = MFMA16(am, bh, acc[nt]);
                acc[nt] = MFMA16(ah, bm, acc[nt]);
                acc[nt] = MFMA16(ah, bh, acc[nt]);
            }
        }
    }
    __syncthreads();
#pragma unroll
    for (int nt = 0; nt < 4; nt++) {
        int col = (ngb + nt) * 16 + lm;
        float b1 = B1[col];
#pragma unroll
        for (int r = 0; r < 4; r++) {
            int row = mt * 16 + quad * 4 + r;
            short h, m, l; split3(gelu_t(acc[nt][r] + b1), h, m, l);
            Ah[row][col] = h; Am[row][col] = m; Al[row][col] = l;
        }
    }
    __syncthreads();
    f32x4 acc2[4];
#pragma unroll
    for (int i = 0; i < 4; i++) acc2[i] = (f32x4)(0.f);
#pragma unroll
    for (int kb = 0; kb < 4; kb++) {
        bf16x8 ah = *(const bf16x8*)&Ah[mt * 16 + lm][kb * 32 + quad * 8];
        bf16x8 am = *(const bf16x8*)&Am[mt * 16 + lm][kb * 32 + quad * 8];
        bf16x8 al = *(const bf16x8*)&Al[mt * 16 + lm][kb * 32 + quad * 8];
#pragma unroll
        for (int nt = 0; nt < 4; nt++) {
            size_t bi = (((size_t)kb * 8 + ngb + nt) * 64 + lane) * 8;
            bf16x8 bh = *(const bf16x8*)&W2h[bi];
            bf16x8 bm = *(const bf16x8*)&W2m[bi];
            bf16x8 bl = *(const bf16x8*)&W2l[bi];
            acc2[nt] = MFMA16(al, bh, acc2[nt]);
            acc2[nt] = MFMA16(am, bm, acc2[nt]);
            acc2[nt] = MFMA16(ah, bl, acc2[nt]);
            acc2[nt] = MFMA16(am, bh, acc2[nt]);
            acc2[nt] = MFMA16(ah, bm, acc2[nt]);
            acc2[nt] = MFMA16(ah, bh, acc2[nt]);
        }
    }
    // epilogue: split3 outputs into LDS, then coalesced tiled-fragment store
    __syncthreads();   // all waves done reading hidden in Ah/Am/Al
#pragma unroll
    for (int nt = 0; nt < 4; nt++) {
        int col = (ngb + nt) * 16 + lm;
        float b2 = B2[col];
#pragma unroll
        for (int r = 0; r < 4; r++) {
            int row = mt * 16 + quad * 4 + r;
            short h, m, l; split3(acc2[nt][r] + b2, h, m, l);
            Ah[row][col] = h; Am[row][col] = m; Al[row][col] = l;
        }
    }
    __syncthreads();
    emit_split_tiles(tid, Ah, Am, Al, Yt, (size_t)bx * 2);
}

// ---------------- single-group encoder body: one (32-token tile, group) per block ----------------
__device__ __forceinline__ void genc_one(
        int bx, int g, char* smem,
        const float* __restrict__ feat,
        const float* __restrict__ gln_g, const float* __restrict__ gln_b,
        const short* __restrict__ W1h, const short* __restrict__ W1m, const short* __restrict__ W1l,
        const float* __restrict__ gb1,
        const short* __restrict__ W2h, const short* __restrict__ W2m, const short* __restrict__ W2l,
        const float* __restrict__ gb2,
        short* __restrict__ Gs) {
    const int tid = threadIdx.x;
    const int wave = tid >> 6, lane = tid & 63;
    const int quad = lane >> 4, lm = lane & 15;
    const int mt = wave & 1;
    const int ngb = (wave >> 1) * 4;
    const int n0 = bx * 32;

    short (*Ah)[136] = (short(*)[136])smem;
    short (*Am)[136] = (short(*)[136])(smem + 8704);
    short (*Al)[136] = (short(*)[136])(smem + 2 * 8704);

    {
        int t = tid >> 3, sub = tid & 7;
        const float* fr = feat + (size_t)(n0 + t) * FDIM + g * FG;
        float xv[FG];
        float mean = 0.f;
#pragma unroll
        for (int i = 0; i < FG; i++) { xv[i] = fr[i]; mean += xv[i]; }
        mean *= (1.0f / FG);
        float var = 0.f;
#pragma unroll
        for (int i = 0; i < FG; i++) { float d = xv[i] - mean; var += d * d; }
        var *= (1.0f / FG);
        float rs = rsqrtf(var + LN_EPS);
#pragma unroll
        for (int j = 0; j < 2; j++) {
            int i = sub * 2 + j;
            float xn = (xv[i] - mean) * rs * gln_g[g * FG + i] + gln_b[g * FG + i];
            short h, m, l; split3(xn, h, m, l);
            Ah[t][i] = h; Am[t][i] = m; Al[t][i] = l;
            Ah[t][16 + i] = 0; Am[t][16 + i] = 0; Al[t][16 + i] = 0;  // K pad to 32
        }
    }
    __syncthreads();
    f32x4 acc[4];
#pragma unroll
    for (int i = 0; i < 4; i++) acc[i] = (f32x4)(0.f);
    {
        bf16x8 ah = *(const bf16x8*)&Ah[mt * 16 + lm][quad * 8];
        bf16x8 am = *(const bf16x8*)&Am[mt * 16 + lm][quad * 8];
        bf16x8 al = *(const bf16x8*)&Al[mt * 16 + lm][quad * 8];
#pragma unroll
        for (int nt = 0; nt < 4; nt++) {
            size_t bi = (((size_t)g * 8 + ngb + nt) * 64 + lane) * 8;  // KB=1 per mat
            bf16x8 bh = *(const bf16x8*)&W1h[bi];
            bf16x8 bm = *(const bf16x8*)&W1m[bi];
            bf16x8 bl = *(const bf16x8*)&W1l[bi];
            acc[nt] = MFMA16(al, bh, acc[nt]);
            acc[nt] = MFMA16(am, bm, acc[nt]);
            acc[nt] = MFMA16(ah, bl, acc[nt]);
            acc[nt] = MFMA16(am, bh, acc[nt]);
            acc[nt] = MFMA16(ah, bm, acc[nt]);
            acc[nt] = MFMA16(ah, bh, acc[nt]);
        }
    }
    __syncthreads();
#pragma unroll
    for (int nt = 0; nt < 4; nt++) {
        int col = (ngb + nt) * 16 + lm;
        float b1 = gb1[g * DH + col];
#pragma unroll
        for (int r = 0; r < 4; r++) {
            int row = mt * 16 + quad * 4 + r;
            short h, m, l; split3(gelu_t(acc[nt][r] + b1), h, m, l);
            Ah[row][col] = h; Am[row][col] = m; Al[row][col] = l;
        }
    }
    __syncthreads();
    f32x4 acc2[4];
#pragma unroll
    for (int i = 0; i < 4; i++) acc2[i] = (f32x4)(0.f);
#pragma unroll
    for (int kb = 0; kb < 4; kb++) {
        bf16x8 a2h = *(const bf16x8*)&Ah[mt * 16 + lm][kb * 32 + quad * 8];
        bf16x8 a2m = *(const bf16x8*)&Am[mt * 16 + lm][kb * 32 + quad * 8];
        bf16x8 a2l = *(const bf16x8*)&Al[mt * 16 + lm][kb * 32 + quad * 8];
#pragma unroll
        for (int nt = 0; nt < 4; nt++) {
            size_t bi = ((((size_t)g * 4 + kb) * 8 + ngb + nt) * 64 + lane) * 8;
            bf16x8 bh = *(const bf16x8*)&W2h[bi];
            bf16x8 bm = *(const bf16x8*)&W2m[bi];
            bf16x8 bl = *(const bf16x8*)&W2l[bi];
            acc2[nt] = MFMA16(a2l, bh, acc2[nt]);
            acc2[nt] = MFMA16(a2m, bm, acc2[nt]);
            acc2[nt] = MFMA16(a2h, bl, acc2[nt]);
            acc2[nt] = MFMA16(a2m, bh, acc2[nt]);
            acc2[nt] = MFMA16(a2h, bm, acc2[nt]);
            acc2[nt] = MFMA16(a2h, bh, acc2[nt]);
        }
    }
    __syncthreads();   // all waves done reading hidden in Ah/Am/Al
#pragma unroll
    for (int nt = 0; nt < 4; nt++) {
        int col = (ngb + nt) * 16 + lm;
        float b2 = gb2[g * DH + col];
#pragma unroll
        for (int r = 0; r < 4; r++) {
            int row = mt * 16 + quad * 4 + r;
            short h, m, l; split3(acc2[nt][r] + b2, h, m, l);
            Ah[row][col] = h; Am[row][col] = m; Al[row][col] = l;
        }
    }
    __syncthreads();
    emit_split_tiles(tid, Ah, Am, Al, Gs, (size_t)g * 256 + bx * 2);
}

// ---------------- fused encoder launch: rh(128) + sf(128) + genc(1024) blocks ----------------
__global__ __launch_bounds__(256) void k_enc_all(
        const float* __restrict__ hL, const float* __restrict__ feat,
        const float* __restrict__ sf_g, const float* __restrict__ sf_b,
        const float* __restrict__ gln_g, const float* __restrict__ gln_b,
        const short* Brh1H, const short* Brh1M, const short* Brh1L, const float* rh_b1,
        const short* Brh2H, const short* Brh2M, const short* Brh2L, const float* rh_b2,
        const short* Bsf1H, const short* Bsf1M, const short* Bsf1L, const float* sf_b1,
        const short* Bsf2H, const short* Bsf2M, const short* Bsf2L, const float* sf_b2,
        const short* Bgf1H, const short* Bgf1M, const short* Bgf1L, const float* gf_b1,
        const short* Bgf2H, const short* Bgf2M, const short* Bgf2L, const float* gf_b2,
        short* __restrict__ Hs, short* __restrict__ Ss, short* __restrict__ Gs) {
    __shared__ __align__(16) char smem[3 * 8704];   // 25.5 KB -> 6 blocks/CU
    int bid = blockIdx.x;
    if (bid < 128)
        enc2_body<16, false>(bid, smem, hL, nullptr, nullptr,
                             Brh1H, Brh1M, Brh1L, rh_b1, Brh2H, Brh2M, Brh2L, rh_b2, Hs);
    else if (bid < 256)
        enc2_body<4, true>(bid - 128, smem, feat, sf_g, sf_b,
                           Bsf1H, Bsf1M, Bsf1L, sf_b1, Bsf2H, Bsf2M, Bsf2L, sf_b2, Ss);
    else {
        int idx = bid - 256;    // (idx & 7) = group -> XCD affinity for gf weights
        genc_one(idx >> 3, idx & 7, smem, feat, gln_g, gln_b,
                 Bgf1H, Bgf1M, Bgf1L, gf_b1, Bgf2H, Bgf2M, Bgf2L, gf_b2, Gs);
    }
}

// ---------------- MFMA router v7: straight-line T14 pipeline, no spills ----------------
// Hand-unrolled 4-chunk schedule; every register array index is compile-time constant.
// Per chunk: { barrier; ds_write staged regs; barrier; issue next chunk's global loads;
//             96 MFMAs }. Loads fly during MFMAs -> barrier drains are free.
// Chunk 3 (h*g) reconstructs fp32 bit-exactly from Hs/Gs splits in VALU after chunk-2 MFMAs.
__global__ __launch_bounds__(512) void k_router_mfma(
        const short* __restrict__ Hs, const short* __restrict__ Ss, const short* __restrict__ Gs,
        const short* __restrict__ BpgH, const short* __restrict__ BpgM, const short* __restrict__ BpgL,
        const short* __restrict__ BirH, const short* __restrict__ BirM, const short* __restrict__ BirL,
        const float* __restrict__ pb1, const float* __restrict__ pw2, const float* __restrict__ pb2,
        const float* __restrict__ ib1, const float* __restrict__ iw2, const float* __restrict__ ib2,
        float* __restrict__ glog, float* __restrict__ ilog) {
    const int g = blockIdx.x & 7;       // group -> XCD affinity for B + Gs
    const int bx = blockIdx.x >> 3;     // 64-token tile (0..63)
    const int n0 = bx * 64;
    const int tid = threadIdx.x;
    const int wave = tid >> 6, lane = tid & 63;
    const int quad = lane >> 4, lm = lane & 15;
    const bool is_pg = wave < 4;
    const int nbase = (wave & 3) * 2;   // 2 n-tiles per wave, 4 waves cover 8
    const short* Bh = is_pg ? BpgH : (BirH + (size_t)g * 65536);
    const short* Bm = is_pg ? BpgM : (BirM + (size_t)g * 65536);
    const short* Bl = is_pg ? BpgL : (BirL + (size_t)g * 65536);

    const short* HsB = Hs + (size_t)bx * 4 * PSTRIDE;
    const short* SsB = Ss + (size_t)bx * 4 * PSTRIDE;
    const short* GsB = Gs + ((size_t)g * 256 + bx * 4) * PSTRIDE;

    // LDS: A staging for one 4-kb chunk: [split 3][kbl 4][t16 4][lane 64][8 shorts] = 48 KB.
    // Epilogue (2 x 32x129 fp32 = 33 KB) aliases it after the K-loop.
    __shared__ __align__(16) char smem[49152];

    // per-thread staging offsets: 6 slots lin = it*512+tid over (split,kbl,t16,lane);
    // LDS byte off = lin*16 (linear = tiled), global short off = tiled-layout address.
    int goff[6];
#pragma unroll
    for (int it = 0; it < 6; it++) {
        int lin = it * 512 + tid;
        int split = lin >> 10, rem = lin & 1023;
        int kbl = rem >> 8, t16 = (rem >> 6) & 3, ln = rem & 63;
        goff[it] = t16 * PSTRIDE + kbl * 1536 + split * 512 + ln * 8;
    }
    // ch3 reconstruction offsets: 2 product-slots slot = t*512+tid over (kbl,t16,lane)
    int roff0, roff1, woff0, woff1;
    {
        int slot = tid;                 // t=0: kbl 0..1
        int kbl = slot >> 8, t16 = (slot >> 6) & 3, ln = slot & 63;
        roff0 = t16 * PSTRIDE + kbl * 1536 + ln * 8;
        woff0 = kbl * 4096 + t16 * 1024 + ln * 16;
        slot = 512 + tid;               // t=1: kbl 2..3
        kbl = slot >> 8; t16 = (slot >> 6) & 3; ln = slot & 63;
        roff1 = t16 * PSTRIDE + kbl * 1536 + ln * 8;
        woff1 = kbl * 4096 + t16 * 1024 + ln * 16;
    }

    f32x4 acc[4][2];
#pragma unroll
    for (int mt = 0; mt < 4; mt++)
#pragma unroll
        for (int nt = 0; nt < 2; nt++) acc[mt][nt] = (f32x4)(0.f);

    bf16x8 R[6];

#define LOADR(basep) { _Pragma("unroll") \
    for (int it = 0; it < 6; it++) R[it] = *(const bf16x8*)((basep) + goff[it]); }
#define STAGE_WRITE() { _Pragma("unroll") \
    for (int it = 0; it < 6; it++) *(bf16x8*)(smem + ((it * 512 + tid) * 16)) = R[it]; }
#define COMPUTE_CHUNK(CH) { _Pragma("unroll") \
    for (int kbl = 0; kbl < 4; kbl++) { \
        const int kb = (CH) * 4 + kbl; \
        bf16x8 Ahf[4], Amf[4], Alf[4]; \
        _Pragma("unroll") \
        for (int mt = 0; mt < 4; mt++) { \
            size_t loff = (size_t)kbl * 4096 + mt * 1024 + (size_t)lane * 16; \
            Ahf[mt] = *(const bf16x8*)(smem + loff); \
            Amf[mt] = *(const bf16x8*)(smem + 16384 + loff); \
            Alf[mt] = *(const bf16x8*)(smem + 32768 + loff); \
        } \
        _Pragma("unroll") \
        for (int nt = 0; nt < 2; nt++) { \
            size_t bi = (((size_t)kb * 8 + nbase + nt) * 64 + lane) * 8; \
            bf16x8 bh = *(const bf16x8*)&Bh[bi]; \
            bf16x8 bm = *(const bf16x8*)&Bm[bi]; \
            bf16x8 bl = *(const bf16x8*)&Bl[bi]; \
            _Pragma("unroll") \
            for (int mt = 0; mt < 4; mt++) { \
                acc[mt][nt] = MFMA16(Alf[mt], bh, acc[mt][nt]); \
                acc[mt][nt] = MFMA16(Amf[mt], bm, acc[mt][nt]); \
                acc[mt][nt] = MFMA16(Ahf[mt], bl, acc[mt][nt]); \
                acc[mt][nt] = MFMA16(Amf[mt], bh, acc[mt][nt]); \
                acc[mt][nt] = MFMA16(Ahf[mt], bm, acc[mt][nt]); \
                acc[mt][nt] = MFMA16(Ahf[mt], bh, acc[mt][nt]); \
            } \
        } \
    } }

    // ---------------- chunk 0 (h_enc) ----------------
    LOADR(HsB);
    STAGE_WRITE();
    __syncthreads();
    LOADR(SsB);                 // prefetch chunk 1 during chunk-0 MFMAs
    COMPUTE_CHUNK(0);

    // ---------------- chunk 1 (s_enc) ----------------
    __syncthreads();
    STAGE_WRITE();
    __syncthreads();
    LOADR(GsB);                 // prefetch chunk 2
    COMPUTE_CHUNK(1);

    // ---------------- chunk 2 (g_enc) ----------------
    __syncthreads();
    STAGE_WRITE();
    __syncthreads();
    // prefetch chunk 3 inputs (h and g splits) -- fly during chunk-2 MFMAs
    bf16x8 Hv0_0 = *(const bf16x8*)(HsB + roff0);
    bf16x8 Hv0_1 = *(const bf16x8*)(HsB + roff0 + 512);
    bf16x8 Hv0_2 = *(const bf16x8*)(HsB + roff0 + 1024);
    bf16x8 Gv0_0 = *(const bf16x8*)(GsB + roff0);
    bf16x8 Gv0_1 = *(const bf16x8*)(GsB + roff0 + 512);
    bf16x8 Gv0_2 = *(const bf16x8*)(GsB + roff0 + 1024);
    bf16x8 Hv1_0 = *(const bf16x8*)(HsB + roff1);
    bf16x8 Hv1_1 = *(const bf16x8*)(HsB + roff1 + 512);
    bf16x8 Hv1_2 = *(const bf16x8*)(HsB + roff1 + 1024);
    bf16x8 Gv1_0 = *(const bf16x8*)(GsB + roff1);
    bf16x8 Gv1_1 = *(const bf16x8*)(GsB + roff1 + 512);
    bf16x8 Gv1_2 = *(const bf16x8*)(GsB + roff1 + 1024);
    COMPUTE_CHUNK(2);

    // reconstruct h*g bit-exactly; VALU work after chunk-2 MFMAs
    bf16x8 P0h, P0m, P0l, P1h, P1m, P1l;
#pragma unroll
    for (int j = 0; j < 8; j++) {
        float hv = bf2f(Hv0_0[j]) + bf2f(Hv0_1[j]) + bf2f(Hv0_2[j]);
        float gv = bf2f(Gv0_0[j]) + bf2f(Gv0_1[j]) + bf2f(Gv0_2[j]);
        short a_, b_, c_; split3(hv * gv, a_, b_, c_);
        P0h[j] = a_; P0m[j] = b_; P0l[j] = c_;
    }
#pragma unroll
    for (int j = 0; j < 8; j++) {
        float hv = bf2f(Hv1_0[j]) + bf2f(Hv1_1[j]) + bf2f(Hv1_2[j]);
        float gv = bf2f(Gv1_0[j]) + bf2f(Gv1_1[j]) + bf2f(Gv1_2[j]);
        short a_, b_, c_; split3(hv * gv, a_, b_, c_);
        P1h[j] = a_; P1m[j] = b_; P1l[j] = c_;
    }

    // ---------------- chunk 3 (h*g) ----------------
    __syncthreads();
    *(bf16x8*)(smem + woff0)         = P0h;
    *(bf16x8*)(smem + 16384 + woff0) = P0m;
    *(bf16x8*)(smem + 32768 + woff0) = P0l;
    *(bf16x8*)(smem + woff1)         = P1h;
    *(bf16x8*)(smem + 16384 + woff1) = P1m;
    *(bf16x8*)(smem + 32768 + woff1) = P1l;
    __syncthreads();
    COMPUTE_CHUNK(3);

#undef LOADR
#undef STAGE_WRITE
#undef COMPUTE_CHUNK

    // epilogue: two 32-row halves reusing staging LDS (ph 32x129 + ih 32x129 = 33 KB)
    float (*ph)[129] = (float(*)[129])smem;
    float (*ih)[129] = (float(*)[129])(smem + 32 * 129 * 4);
    for (int h = 0; h < 2; h++) {
        __syncthreads();   // h=0: K-loop LDS reads done; h=1: prev half's logit reads done
#pragma unroll
        for (int mi = 0; mi < 2; mi++) {
            int mt = 2 * h + mi;
#pragma unroll
            for (int nt = 0; nt < 2; nt++) {
                int col = (nbase + nt) * 16 + lm;
                float b1 = is_pg ? pb1[col] : ib1[g * DH + col];
                float* dst = is_pg ? &ph[0][0] : &ih[0][0];
#pragma unroll
                for (int r = 0; r < 4; r++) {
                    int row = mi * 16 + quad * 4 + r;
                    dst[row * 129 + col] = gelu_t(acc[mt][nt][r] + b1);
                }
            }
        }
        __syncthreads();
        if (tid < 128) {
            // glog dot: 4 lanes per token, 32 i's each, pair-reduce
            int t = tid >> 2, q = tid & 3;
            float s = 0.f;
            for (int i = q * 32; i < q * 32 + 32; i++) s += ph[t][i] * pw2[i];
            s += __shfl_xor(s, 1);
            s += __shfl_xor(s, 2);
            if (q == 0) glog[(size_t)(n0 + h * 32 + t) * G + g] = s + pb2[0]; // TEMP = 1.0
        } else if (tid < 384) {
            // ilog dot: 2 lanes per (token, e), 64 i's each
            int t2 = tid - 128;
            int t = t2 >> 3, e = (t2 >> 1) & 3, half = t2 & 1;
            const float* wv = iw2 + (size_t)g * DH * ES;
            float s = 0.f;
            for (int i = half * 64; i < half * 64 + 64; i++) s += ih[t][i] * wv[i * ES + e];
            s += __shfl_xor(s, 1);
            if (half == 0) ilog[((size_t)(n0 + h * 32 + t) * G + g) * ES + e] = s + ib2[g * ES + e];
        }
    }
}

// ---------------- top-k softmax + dispatch to per-expert lists ----------------
__global__ void k_topk(const float* __restrict__ glog, const float* __restrict__ ilog,
                       int* __restrict__ cnt, int* __restrict__ toks, float* __restrict__ wgts) {
    int n = blockIdx.x * blockDim.x + threadIdx.x;
    if (n >= N_TOK) return;
    float gl[G];
#pragma unroll
    for (int g = 0; g < G; g++) gl[g] = glog[(size_t)n * G + g];
    int i1 = 0; float v1 = gl[0];
#pragma unroll
    for (int g = 1; g < G; g++) if (gl[g] > v1) { v1 = gl[g]; i1 = g; }
    int i2 = -1; float v2 = -1e30f;
#pragma unroll
    for (int g = 0; g < G; g++) if (g != i1 && gl[g] > v2) { v2 = gl[g]; i2 = g; }
    float eg = expf(v2 - v1);
    float den = 1.0f / (1.0f + eg);
    float gw_sel[2] = { den, eg * den };
    int g_sel[2] = { i1, i2 };
#pragma unroll
    for (int s = 0; s < 2; s++) {
        int g = g_sel[s]; float gw = gw_sel[s];
        float il[ES];
#pragma unroll
        for (int e = 0; e < ES; e++) il[e] = ilog[((size_t)n * G + g) * ES + e];
        int j1 = 0; float u1 = il[0];
#pragma unroll
        for (int e = 1; e < ES; e++) if (il[e] > u1) { u1 = il[e]; j1 = e; }
        int j2 = -1; float u2 = -1e30f;
#pragma unroll
        for (int e = 0; e < ES; e++) if (e != j1 && il[e] > u2) { u2 = il[e]; j2 = e; }
        float ei = expf(u2 - u1);
        float d2 = 1.0f / (1.0f + ei);
        int ex1 = g * ES + j1, ex2 = g * ES + j2;
        int p1 = atomicAdd(&cnt[ex1], 1);
        toks[(size_t)ex1 * N_TOK + p1] = n * 4 + s * 2;     wgts[(size_t)ex1 * N_TOK + p1] = gw * d2;
        int p2 = atomicAdd(&cnt[ex2], 1);
        toks[(size_t)ex2 * N_TOK + p2] = n * 4 + s * 2 + 1; wgts[(size_t)ex2 * N_TOK + p2] = gw * ei * d2;
    }
}

// ---------------- sparse expert MLPs via bf16 MFMA; XCD-swizzled; es aliases hs (33KB LDS) ----------------
__global__ __launch_bounds__(512) void k_expert_mfma(
        const __hip_bfloat16* __restrict__ h_normb,
        const short* __restrict__ wB1, const float* __restrict__ eb1,
        const short* __restrict__ wB2, const float* __restrict__ eb2,
        const int* __restrict__ cnt, const int* __restrict__ toks,
        const float* __restrict__ wgts, float* __restrict__ part) {
    const int e = blockIdx.x & 31;
    const int slot = blockIdx.x >> 5;
    const int c = cnt[e];
    const int start = slot * BT;
    if (start >= c) return;
    const int m = min(BT, c - start);

    __shared__ short hs[BT][520];                   // 33.3 KB; es aliases (dead after phase 1)
    short (*es)[264] = (short(*)[264])&hs[0][0];    // 16.9 KB
    __shared__ int   tok_s[BT];
    __shared__ float w_s[BT];

    const int tid = threadIdx.x;
    if (tid < BT) {
        bool ok = tid < m;
        tok_s[tid] = ok ? toks[(size_t)e * N_TOK + start + tid] : 0;
        w_s[tid]   = ok ? wgts[(size_t)e * N_TOK + start + tid] : 0.f;
    }
    __syncthreads();
    for (int idx = tid; idx < BT * 64; idx += 512) {
        int t = idx >> 6, ch = idx & 63;
        uint4 v = make_uint4(0, 0, 0, 0);
        if (t < m) v = *((const uint4*)(h_normb + (size_t)(tok_s[t] >> 2) * DM) + ch);
        *(uint4*)&hs[t][ch * 8] = v;
    }
    __syncthreads();

    const int wave = tid >> 6, lane = tid & 63;
    const int quad = lane >> 4, lm = lane & 15;

    // ---- phase 1: acc = hs @ W1 (reads hs) ----
    const int ng = wave * 2;
    f32x4 acc1[2][2];
#pragma unroll
    for (int a = 0; a < 2; a++)
#pragma unroll
        for (int b = 0; b < 2; b++) acc1[a][b] = (f32x4)(0.f);
    {
        const short* w1e = wB1 + (size_t)e * DM * DE;
        for (int kb = 0; kb < 16; kb++) {
            bf16x8 a0 = *(const bf16x8*)&hs[lm][kb * 32 + quad * 8];
            bf16x8 a1 = *(const bf16x8*)&hs[16 + lm][kb * 32 + quad * 8];
            const short* wp = w1e + ((size_t)kb * 16 + ng) * 512 + lane * 8;
#pragma unroll
            for (int nt = 0; nt < 2; nt++) {
                bf16x8 b = *(const bf16x8*)(wp + nt * 512);
                acc1[0][nt] = MFMA16(a0, b, acc1[0][nt]);
                acc1[1][nt] = MFMA16(a1, b, acc1[1][nt]);
            }
        }
    }
    __syncthreads();   // all waves done reading hs before es overwrite
#pragma unroll
    for (int nt = 0; nt < 2; nt++) {
        int col = (ng + nt) * 16 + lm;
        float b1 = eb1[e * DE + col];
#pragma unroll
        for (int mt = 0; mt < 2; mt++)
#pragma unroll
        for (int r = 0; r < 4; r++) {
            int row = mt * 16 + quad * 4 + r;
            es[row][col] = f2bf(gelu_t(acc1[mt][nt][r] + b1));
        }
    }
    __syncthreads();

    // ---- phase 2: part[tok] = w * (es @ W2 + b2) ----
    {
        const int ng2 = wave * 4;
        f32x4 acc[2][4];
#pragma unroll
        for (int a = 0; a < 2; a++)
#pragma unroll
            for (int b = 0; b < 4; b++) acc[a][b] = (f32x4)(0.f);
        const short* w2e = wB2 + (size_t)e * DE * DM;
        for (int kb = 0; kb < 8; kb++) {
            bf16x8 a0 = *(const bf16x8*)&es[lm][kb * 32 + quad * 8];
            bf16x8 a1 = *(const bf16x8*)&es[16 + lm][kb * 32 + quad * 8];
            const short* wp = w2e + ((size_t)kb * 32 + ng2) * 512 + lane * 8;
#pragma unroll
            for (int nt = 0; nt < 4; nt++) {
                bf16x8 b = *(const bf16x8*)(wp + nt * 512);
                acc[0][nt] = MFMA16(a0, b, acc[0][nt]);
                acc[1][nt] = MFMA16(a1, b, acc[1][nt]);
            }
        }
        const float* b2 = eb2 + (size_t)e * DM;
#pragma unroll
        for (int mt = 0; mt < 2; mt++)
#pragma unroll
        for (int r = 0; r < 4; r++) {
            int row = mt * 16 + quad * 4 + r;
            if (row < m) {
                float w = w_s[row];
                float* prow = part + (size_t)tok_s[row] * DM;
#pragma unroll
                for (int nt = 0; nt < 4; nt++) {
                    int col = (ng2 + nt) * 16 + lm;
                    prow[col] = w * (acc[mt][nt][r] + b2[col]);
                }
            }
        }
    }
}

// ---------------- final reduce: out[n] = sum_s part[n*4+s] ----------------
__global__ void k_reduce(const float* __restrict__ part, float* __restrict__ out) {
    int n = blockIdx.x;
    int j = threadIdx.x; // 0..127
    const float4* p = (const float4*)(part + (size_t)n * 4 * DM);
    float4 a = p[j], b = p[128 + j], c = p[256 + j], d = p[384 + j];
    float4 r = make_float4(a.x + b.x + c.x + d.x, a.y + b.y + c.y + d.y,
                           a.z + b.z + c.z + d.z, a.w + b.w + c.w + d.w);
    ((float4*)(out + (size_t)n * DM))[j] = r;
}

extern "C" void kernel_launch(void* const* d_in, const int* in_sizes, int n_in,
                              void* d_out, int out_size, void* d_ws, size_t ws_size,
                              hipStream_t stream) {
    const float* hidden  = (const float*)d_in[0];
    const float* feat    = (const float*)d_in[1];
    const float* pre_g   = (const float*)d_in[2];
    const float* pre_b   = (const float*)d_in[3];
    const float* rh_g    = (const float*)d_in[4];
    const float* rh_b    = (const float*)d_in[5];
    const float* rh_w1   = (const float*)d_in[6];
    const float* rh_b1   = (const float*)d_in[7];
    const float* rh_w2   = (const float*)d_in[8];
    const float* rh_b2   = (const float*)d_in[9];
    const float* sf_g    = (const float*)d_in[10];
    const float* sf_b    = (const float*)d_in[11];
    const float* sf_w1   = (const float*)d_in[12];
    const float* sf_b1   = (const float*)d_in[13];
    const float* sf_w2   = (const float*)d_in[14];
    const float* sf_b2   = (const float*)d_in[15];
    const float* gln_g   = (const float*)d_in[16];
    const float* gln_b   = (const float*)d_in[17];
    const float* gf_w1   = (const float*)d_in[18];
    const float* gf_b1   = (const float*)d_in[19];
    const float* gf_w2   = (const float*)d_in[20];
    const float* gf_b2   = (const float*)d_in[21];
    const float* pgs_w1  = (const float*)d_in[22];
    const float* pgs_b1  = (const float*)d_in[23];
    const float* pgs_w2  = (const float*)d_in[24];
    const float* pgs_b2  = (const float*)d_in[25];
    const float* ir_w1   = (const float*)d_in[26];
    const float* ir_b1   = (const float*)d_in[27];
    const float* ir_w2   = (const float*)d_in[28];
    const float* ir_b2   = (const float*)d_in[29];
    const float* ex_w1   = (const float*)d_in[30];
    const float* ex_b1   = (const float*)d_in[31];
    const float* ex_w2   = (const float*)d_in[32];
    const float* ex_b2   = (const float*)d_in[33];
    float* out = (float*)d_out;

    // workspace carving (256B-aligned)
    char* w = (char*)d_ws;
    auto alloc = [&](size_t bytes) { void* r = (void*)w; w += (bytes + 255) & ~(size_t)255; return r; };
    __hip_bfloat16* h_normb = (__hip_bfloat16*)alloc((size_t)N_TOK * DM * 2);
    short* Hs    = (short*)alloc((size_t)256 * PSTRIDE * 2);   // 3 MB tiled split3 h_enc
    short* Ss    = (short*)alloc((size_t)256 * PSTRIDE * 2);   // 3 MB tiled split3 s_enc
    float* glog  = (float*)alloc((size_t)N_TOK * G * 4);
    float* ilog  = (float*)alloc((size_t)N_TOK * G * ES * 4);
    float* wgts  = (float*)alloc((size_t)E_EXP * N_TOK * 4);
    short* wB1   = (short*)alloc((size_t)E_EXP * DM * DE * 2);
    short* wB2   = (short*)alloc((size_t)E_EXP * DE * DM * 2);
    short* BpgH  = (short*)alloc((size_t)16 * 8 * 512 * 2);
    short* BpgM  = (short*)alloc((size_t)16 * 8 * 512 * 2);
    short* BpgL  = (short*)alloc((size_t)16 * 8 * 512 * 2);
    short* BirH  = (short*)alloc((size_t)G * 16 * 8 * 512 * 2);
    short* BirM  = (short*)alloc((size_t)G * 16 * 8 * 512 * 2);
    short* BirL  = (short*)alloc((size_t)G * 16 * 8 * 512 * 2);
    short* Brh1H = (short*)alloc((size_t)16 * 8 * 512 * 2);
    short* Brh1M = (short*)alloc((size_t)16 * 8 * 512 * 2);
    short* Brh1L = (short*)alloc((size_t)16 * 8 * 512 * 2);
    short* Brh2H = (short*)alloc((size_t)4 * 8 * 512 * 2);
    short* Brh2M = (short*)alloc((size_t)4 * 8 * 512 * 2);
    short* Brh2L = (short*)alloc((size_t)4 * 8 * 512 * 2);
    short* Bsf1H = (short*)alloc((size_t)4 * 8 * 512 * 2);
    short* Bsf1M = (short*)alloc((size_t)4 * 8 * 512 * 2);
    short* Bsf1L = (short*)alloc((size_t)4 * 8 * 512 * 2);
    short* Bsf2H = (short*)alloc((size_t)4 * 8 * 512 * 2);
    short* Bsf2M = (short*)alloc((size_t)4 * 8 * 512 * 2);
    short* Bsf2L = (short*)alloc((size_t)4 * 8 * 512 * 2);
    short* Bgf1H = (short*)alloc((size_t)G * 1 * 8 * 512 * 2);
    short* Bgf1M = (short*)alloc((size_t)G * 1 * 8 * 512 * 2);
    short* Bgf1L = (short*)alloc((size_t)G * 1 * 8 * 512 * 2);
    short* Bgf2H = (short*)alloc((size_t)G * 4 * 8 * 512 * 2);
    short* Bgf2M = (short*)alloc((size_t)G * 4 * 8 * 512 * 2);
    short* Bgf2L = (short*)alloc((size_t)G * 4 * 8 * 512 * 2);
    int* cnt     = (int*)alloc(E_EXP * 4);
    int* toks    = (int*)alloc((size_t)E_EXP * N_TOK * 4);
    // union region (disjoint live ranges, stream-ordered):
    //   hL   [k_pre -> k_enc_all]           8.4 MB  (front of uni)
    //   Gs   [k_enc_all -> k_router_mfma]  24.0 MB  (uni + 8.4 MB)
    //   part [k_expert_mfma -> k_reduce]   33.6 MB  (all of uni)
    char* uni   = (char*)alloc((size_t)N_TOK * 4 * DM * 4); // 33.6 MB = max
    float* hL   = (float*)uni;
    short* Gs   = (short*)(uni + (size_t)N_TOK * DM * 4);   // 24 MB tiled split3 g_enc
    float* part = (float*)uni;

    hipMemsetAsync(cnt, 0, E_EXP * sizeof(int), stream);

    // fused pre-pass: 10 weight-conversion jobs + 4096 LN blocks, one launch
    ConvJobs J;
    int b0 = 0;
    auto mkjob = [&](int i, const float* s, short* dh, short* dm, short* dl,
                     int KB, int NB, int Kreal, int plain, int nmat) {
        J.j[i] = ConvJob{s, dh, dm, dl, KB, NB, Kreal, plain, b0};
        b0 += KB * nmat;
    };
    mkjob(0, ex_w1, wB1, nullptr, nullptr, 16, 16, 512, 1, E_EXP);
    mkjob(1, ex_w2, wB2, nullptr, nullptr, 8, 32, 256, 1, E_EXP);
    mkjob(2, pgs_w1, BpgH, BpgM, BpgL, 16, 8, 512, 0, 1);
    mkjob(3, ir_w1, BirH, BirM, BirL, 16, 8, 512, 0, G);
    mkjob(4, rh_w1, Brh1H, Brh1M, Brh1L, 16, 8, 512, 0, 1);
    mkjob(5, rh_w2, Brh2H, Brh2M, Brh2L, 4, 8, 128, 0, 1);
    mkjob(6, sf_w1, Bsf1H, Bsf1M, Bsf1L, 4, 8, 128, 0, 1);
    mkjob(7, sf_w2, Bsf2H, Bsf2M, Bsf2L, 4, 8, 128, 0, 1);
    mkjob(8, gf_w1, Bgf1H, Bgf1M, Bgf1L, 1, 8, 16, 0, G);
    mkjob(9, gf_w2, Bgf2H, Bgf2M, Bgf2L, 4, 8, 128, 0, G);
    k_pre<<<b0 + N_TOK, 256, 0, stream>>>(J, b0, hidden, pre_g, pre_b, rh_g, rh_b, h_normb, hL);

    // fused encoders: rh(128) + sf(128) + per-(tile,group) genc(1024) = 1280 blocks
    k_enc_all<<<256 + (N_TOK / 32) * G, 256, 0, stream>>>(
        hL, feat, sf_g, sf_b, gln_g, gln_b,
        Brh1H, Brh1M, Brh1L, rh_b1, Brh2H, Brh2M, Brh2L, rh_b2,
        Bsf1H, Bsf1M, Bsf1L, sf_b1, Bsf2H, Bsf2M, Bsf2L, sf_b2,
        Bgf1H, Bgf1M, Bgf1L, gf_b1, Bgf2H, Bgf2M, Bgf2L, gf_b2,
        Hs, Ss, Gs);

    // router v7: 64-token tiles, 512 threads, straight-line T14 pipeline
    k_router_mfma<<<(N_TOK / 64) * G, 512, 0, stream>>>(Hs, Ss, Gs,
                                             BpgH, BpgM, BpgL, BirH, BirM, BirL,
                                             pgs_b1, pgs_w2, pgs_b2, ir_b1, ir_w2, ir_b2,
                                             glog, ilog);

    k_topk<<<N_TOK / 256, 256, 0, stream>>>(glog, ilog, cnt, toks, wgts);
    // XCD-swizzled 1D expert grid: bid = slot*32 + e
    k_expert_mfma<<<(N_TOK / BT) * E_EXP, 512, 0, stream>>>(h_normb, wB1, ex_b1, wB2, ex_b2,
                                                            cnt, toks, wgts, part);
    k_reduce<<<N_TOK, 128, 0, stream>>>(part, out);
}

// Round 4
// 336.245 us; speedup vs baseline: 1.3613x; 1.0278x over previous
//
#include <hip/hip_runtime.h>
#include <hip/hip_bf16.h>
#include <math.h>

#define N_TOK 4096
#define DM 512
#define FDIM 128
#define G 8
#define FG 16
#define DH 128
#define DE 256
#define ES 4
#define E_EXP 32
#define LN_EPS 1e-5f
#define BT 32   // expert token tile (MFMA)

typedef __attribute__((ext_vector_type(8))) short bf16x8;  // 8 bf16 = 4 VGPRs
typedef __attribute__((ext_vector_type(4))) float f32x4;

#define MFMA16(a, b, c) __builtin_amdgcn_mfma_f32_16x16x32_bf16((a), (b), (c), 0, 0, 0)

__device__ __forceinline__ float gelu_t(float x) {
    const float c = 0.7978845608028654f; // sqrt(2/pi)
    float x3 = x * x * x;
    return 0.5f * x * (1.0f + tanhf(c * (x + 0.044715f * x3)));
}

__device__ __forceinline__ short f2bf(float f) {
    __hip_bfloat16 h = __float2bfloat16(f);
    return *reinterpret_cast<short*>(&h);
}
__device__ __forceinline__ float bf2f(short s) {
    __hip_bfloat16 h = *reinterpret_cast<__hip_bfloat16*>(&s);
    return __bfloat162float(h);
}
// exact 3-way split: x == bf2f(h)+bf2f(m)+bf2f(l) bit-exactly for fp32 x
__device__ __forceinline__ void split3(float x, short& h, short& m, short& l) {
    h = f2bf(x);
    float r = x - bf2f(h);   // exact in fp32
    m = f2bf(r);
    float r2 = r - bf2f(m);  // exact; <=6 significant bits remain
    l = f2bf(r2);            // exact
}

// ---------------- fused pre-pass: weight conversion jobs + LN(hidden) ----------------
struct ConvJob { const float* src; short* dh; short* dm; short* dl;
                 int KB, NB, Kreal, plain, blk0; };
struct ConvJobs { ConvJob j[10]; };

__global__ void k_pre(ConvJobs J, int nconv,
                      const float* __restrict__ hidden,
                      const float* __restrict__ pg, const float* __restrict__ pb,
                      const float* __restrict__ rg, const float* __restrict__ rb,
                      __hip_bfloat16* __restrict__ h_normb, float* __restrict__ hL) {
    int b = blockIdx.x;
    if (b >= nconv) {
        // -------- LN of hidden: pre_ln -> h_norm (bf16) and rh_ln -> hL (fp32) --------
        int n = b - nconv;
        int j = threadIdx.x; // 0..255
        const float* x = hidden + (size_t)n * DM;
        float v0 = x[j], v1 = x[j + 256];
        float s = v0 + v1, q = v0 * v0 + v1 * v1;
#pragma unroll
        for (int o = 32; o; o >>= 1) { s += __shfl_down(s, o); q += __shfl_down(q, o); }
        __shared__ float red[8];
        int w = j >> 6;
        if ((j & 63) == 0) { red[w] = s; red[4 + w] = q; }
        __syncthreads();
        float sum = red[0] + red[1] + red[2] + red[3];
        float sq  = red[4] + red[5] + red[6] + red[7];
        float m = sum * (1.0f / DM);
        float var = sq * (1.0f / DM) - m * m;
        float rs = rsqrtf(var + LN_EPS);
        float t0 = (v0 - m) * rs, t1 = (v1 - m) * rs;
        size_t base = (size_t)n * DM;
        h_normb[base + j]       = __float2bfloat16(t0 * pg[j]       + pb[j]);
        h_normb[base + j + 256] = __float2bfloat16(t1 * pg[j + 256] + pb[j + 256]);
        hL[base + j]           = t0 * rg[j]       + rb[j];
        hL[base + j + 256]     = t1 * rg[j + 256] + rb[j + 256];
        return;
    }
    // -------- weight conversion: plain bf16 or 3-way split, K zero-pad --------
    int ji = 0;
#pragma unroll
    for (int i = 1; i < 10; i++) if (b >= J.j[i].blk0) ji = i;
    const ConvJob jb = J.j[ji];
    int rel = b - jb.blk0;
    int mat = rel / jb.KB, kb = rel % jb.KB;
    int ncols = jb.NB * 16;
    const float* s = jb.src + (size_t)mat * jb.Kreal * ncols;
    size_t dbase = ((size_t)mat * jb.KB + kb) * jb.NB * 512;
    for (int p = threadIdx.x; p < jb.NB * 64; p += 256) {
        int nb = p >> 6, lane = p & 63;
        int row0 = kb * 32 + ((lane >> 4) << 3);
        int col = nb * 16 + (lane & 15);
        if (jb.plain) {
            union { short sh[8]; uint4 v; } t;
#pragma unroll
            for (int j = 0; j < 8; j++) {
                float x = (row0 + j < jb.Kreal) ? s[(size_t)(row0 + j) * ncols + col] : 0.f;
                t.sh[j] = f2bf(x);
            }
            *(uint4*)&jb.dh[dbase + (size_t)p * 8] = t.v;
        } else {
            union { short sh[8]; uint4 v; } hi, mi, lo;
#pragma unroll
            for (int j = 0; j < 8; j++) {
                float x = (row0 + j < jb.Kreal) ? s[(size_t)(row0 + j) * ncols + col] : 0.f;
                split3(x, hi.sh[j], mi.sh[j], lo.sh[j]);
            }
            *(uint4*)&jb.dh[dbase + (size_t)p * 8] = hi.v;
            *(uint4*)&jb.dm[dbase + (size_t)p * 8] = mi.v;
            *(uint4*)&jb.dl[dbase + (size_t)p * 8] = lo.v;
        }
    }
}

// ---------------- 2-layer MLP body via 3-split MFMA: Y = gelu(LN?(X)@W1+b1)@W2+b2 ----------------
template <int KB_TOT, bool DO_LN>
__device__ __forceinline__ void enc2_body(
        int bx, char* smem,
        const float* __restrict__ X,
        const float* __restrict__ lng, const float* __restrict__ lnb,
        const short* __restrict__ W1h, const short* __restrict__ W1m, const short* __restrict__ W1l,
        const float* __restrict__ B1,
        const short* __restrict__ W2h, const short* __restrict__ W2m, const short* __restrict__ W2l,
        const float* __restrict__ B2,
        float* __restrict__ Y) {
    constexpr int K = KB_TOT * 32;
    const int n0 = bx * 32;
    const int tid = threadIdx.x;
    const int wave = tid >> 6, lane = tid & 63;
    const int quad = lane >> 4, lm = lane & 15;
    const int mt = wave & 1;
    const int ngb = (wave >> 1) * 4;   // 4 n-tiles per wave

    short (*Ah)[132] = (short(*)[132])smem;
    short (*Am)[132] = (short(*)[132])(smem + 32 * 132 * 2);
    short (*Al)[132] = (short(*)[132])(smem + 2 * 32 * 132 * 2);

    f32x4 acc[4];
#pragma unroll
    for (int i = 0; i < 4; i++) acc[i] = (f32x4)(0.f);

    if (DO_LN) {
        for (int idx = tid; idx < 1024; idx += 256) {
            int row = idx >> 5, c4 = (idx & 31) * 4;
            float4 v = *(const float4*)&X[(size_t)(n0 + row) * K + c4];
            float s = v.x + v.y + v.z + v.w;
            float q = v.x * v.x + v.y * v.y + v.z * v.z + v.w * v.w;
#pragma unroll
            for (int o = 16; o; o >>= 1) { s += __shfl_xor(s, o); q += __shfl_xor(q, o); }
            float mean = s * (1.0f / 128.0f);
            float var = q * (1.0f / 128.0f) - mean * mean;
            float rs = rsqrtf(var + LN_EPS);
            float xv[4] = {(v.x - mean) * rs * lng[c4 + 0] + lnb[c4 + 0],
                           (v.y - mean) * rs * lng[c4 + 1] + lnb[c4 + 1],
                           (v.z - mean) * rs * lng[c4 + 2] + lnb[c4 + 2],
                           (v.w - mean) * rs * lng[c4 + 3] + lnb[c4 + 3]};
#pragma unroll
            for (int j = 0; j < 4; j++) {
                short h, m, l; split3(xv[j], h, m, l);
                Ah[row][c4 + j] = h; Am[row][c4 + j] = m; Al[row][c4 + j] = l;
            }
        }
        __syncthreads();
#pragma unroll
        for (int kb = 0; kb < KB_TOT; kb++) {
            bf16x8 ah = *(const bf16x8*)&Ah[mt * 16 + lm][kb * 32 + quad * 8];
            bf16x8 am = *(const bf16x8*)&Am[mt * 16 + lm][kb * 32 + quad * 8];
            bf16x8 al = *(const bf16x8*)&Al[mt * 16 + lm][kb * 32 + quad * 8];
#pragma unroll
            for (int nt = 0; nt < 4; nt++) {
                size_t bi = (((size_t)kb * 8 + ngb + nt) * 64 + lane) * 8;
                bf16x8 bh = *(const bf16x8*)&W1h[bi];
                bf16x8 bm = *(const bf16x8*)&W1m[bi];
                bf16x8 bl = *(const bf16x8*)&W1l[bi];
                acc[nt] = MFMA16(al, bh, acc[nt]);
                acc[nt] = MFMA16(am, bm, acc[nt]);
                acc[nt] = MFMA16(ah, bl, acc[nt]);
                acc[nt] = MFMA16(am, bh, acc[nt]);
                acc[nt] = MFMA16(ah, bm, acc[nt]);
                acc[nt] = MFMA16(ah, bh, acc[nt]);
            }
        }
    } else {
        for (int kb = 0; kb < KB_TOT; kb++) {
            const float* xs = X + (size_t)(n0 + mt * 16 + lm) * K + kb * 32 + quad * 8;
            float4 x0 = *(const float4*)xs, x1 = *(const float4*)(xs + 4);
            float xv[8] = {x0.x, x0.y, x0.z, x0.w, x1.x, x1.y, x1.z, x1.w};
            bf16x8 ah, am, al;
#pragma unroll
            for (int j = 0; j < 8; j++) {
                short h, m, l; split3(xv[j], h, m, l);
                ah[j] = h; am[j] = m; al[j] = l;
            }
#pragma unroll
            for (int nt = 0; nt < 4; nt++) {
                size_t bi = (((size_t)kb * 8 + ngb + nt) * 64 + lane) * 8;
                bf16x8 bh = *(const bf16x8*)&W1h[bi];
                bf16x8 bm = *(const bf16x8*)&W1m[bi];
                bf16x8 bl = *(const bf16x8*)&W1l[bi];
                acc[nt] = MFMA16(al, bh, acc[nt]);
                acc[nt] = MFMA16(am, bm, acc[nt]);
                acc[nt] = MFMA16(ah, bl, acc[nt]);
                acc[nt] = MFMA16(am, bh, acc[nt]);
                acc[nt] = MFMA16(ah, bm, acc[nt]);
                acc[nt] = MFMA16(ah, bh, acc[nt]);
            }
        }
    }
    __syncthreads();
#pragma unroll
    for (int nt = 0; nt < 4; nt++) {
        int col = (ngb + nt) * 16 + lm;
        float b1 = B1[col];
#pragma unroll
        for (int r = 0; r < 4; r++) {
            int row = mt * 16 + quad * 4 + r;
            short h, m, l; split3(gelu_t(acc[nt][r] + b1), h, m, l);
            Ah[row][col] = h; Am[row][col] = m; Al[row][col] = l;
        }
    }
    __syncthreads();
    f32x4 acc2[4];
#pragma unroll
    for (int i = 0; i < 4; i++) acc2[i] = (f32x4)(0.f);
#pragma unroll
    for (int kb = 0; kb < 4; kb++) {
        bf16x8 ah = *(const bf16x8*)&Ah[mt * 16 + lm][kb * 32 + quad * 8];
        bf16x8 am = *(const bf16x8*)&Am[mt * 16 + lm][kb * 32 + quad * 8];
        bf16x8 al = *(const bf16x8*)&Al[mt * 16 + lm][kb * 32 + quad * 8];
#pragma unroll
        for (int nt = 0; nt < 4; nt++) {
            size_t bi = (((size_t)kb * 8 + ngb + nt) * 64 + lane) * 8;
            bf16x8 bh = *(const bf16x8*)&W2h[bi];
            bf16x8 bm = *(const bf16x8*)&W2m[bi];
            bf16x8 bl = *(const bf16x8*)&W2l[bi];
            acc2[nt] = MFMA16(al, bh, acc2[nt]);
            acc2[nt] = MFMA16(am, bm, acc2[nt]);
            acc2[nt] = MFMA16(ah, bl, acc2[nt]);
            acc2[nt] = MFMA16(am, bh, acc2[nt]);
            acc2[nt] = MFMA16(ah, bm, acc2[nt]);
            acc2[nt] = MFMA16(ah, bh, acc2[nt]);
        }
    }
#pragma unroll
    for (int nt = 0; nt < 4; nt++) {
        int col = (ngb + nt) * 16 + lm;
        float b2 = B2[col];
#pragma unroll
        for (int r = 0; r < 4; r++) {
            int row = mt * 16 + quad * 4 + r;
            Y[(size_t)(n0 + row) * DH + col] = acc2[nt][r] + b2;
        }
    }
}

// ---------------- single-group encoder body: one (32-token tile, group) per block ----------------
__device__ __forceinline__ void genc_one(
        int bx, int g, char* smem,
        const float* __restrict__ feat,
        const float* __restrict__ gln_g, const float* __restrict__ gln_b,
        const short* __restrict__ W1h, const short* __restrict__ W1m, const short* __restrict__ W1l,
        const float* __restrict__ gb1,
        const short* __restrict__ W2h, const short* __restrict__ W2m, const short* __restrict__ W2l,
        const float* __restrict__ gb2,
        float* __restrict__ g_enc) {
    const int tid = threadIdx.x;
    const int wave = tid >> 6, lane = tid & 63;
    const int quad = lane >> 4, lm = lane & 15;
    const int mt = wave & 1;
    const int ngb = (wave >> 1) * 4;
    const int n0 = bx * 32;

    short (*Ah)[132] = (short(*)[132])smem;
    short (*Am)[132] = (short(*)[132])(smem + 8448);
    short (*Al)[132] = (short(*)[132])(smem + 2 * 8448);

    {
        int t = tid >> 3, sub = tid & 7;
        const float* fr = feat + (size_t)(n0 + t) * FDIM + g * FG;
        float xv[FG];
        float mean = 0.f;
#pragma unroll
        for (int i = 0; i < FG; i++) { xv[i] = fr[i]; mean += xv[i]; }
        mean *= (1.0f / FG);
        float var = 0.f;
#pragma unroll
        for (int i = 0; i < FG; i++) { float d = xv[i] - mean; var += d * d; }
        var *= (1.0f / FG);
        float rs = rsqrtf(var + LN_EPS);
#pragma unroll
        for (int j = 0; j < 2; j++) {
            int i = sub * 2 + j;
            float xn = (xv[i] - mean) * rs * gln_g[g * FG + i] + gln_b[g * FG + i];
            short h, m, l; split3(xn, h, m, l);
            Ah[t][i] = h; Am[t][i] = m; Al[t][i] = l;
            Ah[t][16 + i] = 0; Am[t][16 + i] = 0; Al[t][16 + i] = 0;  // K pad to 32
        }
    }
    __syncthreads();
    f32x4 acc[4];
#pragma unroll
    for (int i = 0; i < 4; i++) acc[i] = (f32x4)(0.f);
    {
        bf16x8 ah = *(const bf16x8*)&Ah[mt * 16 + lm][quad * 8];
        bf16x8 am = *(const bf16x8*)&Am[mt * 16 + lm][quad * 8];
        bf16x8 al = *(const bf16x8*)&Al[mt * 16 + lm][quad * 8];
#pragma unroll
        for (int nt = 0; nt < 4; nt++) {
            size_t bi = (((size_t)g * 8 + ngb + nt) * 64 + lane) * 8;  // KB=1 per mat
            bf16x8 bh = *(const bf16x8*)&W1h[bi];
            bf16x8 bm = *(const bf16x8*)&W1m[bi];
            bf16x8 bl = *(const bf16x8*)&W1l[bi];
            acc[nt] = MFMA16(al, bh, acc[nt]);
            acc[nt] = MFMA16(am, bm, acc[nt]);
            acc[nt] = MFMA16(ah, bl, acc[nt]);
            acc[nt] = MFMA16(am, bh, acc[nt]);
            acc[nt] = MFMA16(ah, bm, acc[nt]);
            acc[nt] = MFMA16(ah, bh, acc[nt]);
        }
    }
    __syncthreads();
#pragma unroll
    for (int nt = 0; nt < 4; nt++) {
        int col = (ngb + nt) * 16 + lm;
        float b1 = gb1[g * DH + col];
#pragma unroll
        for (int r = 0; r < 4; r++) {
            int row = mt * 16 + quad * 4 + r;
            short h, m, l; split3(gelu_t(acc[nt][r] + b1), h, m, l);
            Ah[row][col] = h; Am[row][col] = m; Al[row][col] = l;
        }
    }
    __syncthreads();
    f32x4 acc2[4];
#pragma unroll
    for (int i = 0; i < 4; i++) acc2[i] = (f32x4)(0.f);
#pragma unroll
    for (int kb = 0; kb < 4; kb++) {
        bf16x8 a2h = *(const bf16x8*)&Ah[mt * 16 + lm][kb * 32 + quad * 8];
        bf16x8 a2m = *(const bf16x8*)&Am[mt * 16 + lm][kb * 32 + quad * 8];
        bf16x8 a2l = *(const bf16x8*)&Al[mt * 16 + lm][kb * 32 + quad * 8];
#pragma unroll
        for (int nt = 0; nt < 4; nt++) {
            size_t bi = ((((size_t)g * 4 + kb) * 8 + ngb + nt) * 64 + lane) * 8;
            bf16x8 bh = *(const bf16x8*)&W2h[bi];
            bf16x8 bm = *(const bf16x8*)&W2m[bi];
            bf16x8 bl = *(const bf16x8*)&W2l[bi];
            acc2[nt] = MFMA16(a2l, bh, acc2[nt]);
            acc2[nt] = MFMA16(a2m, bm, acc2[nt]);
            acc2[nt] = MFMA16(a2h, bl, acc2[nt]);
            acc2[nt] = MFMA16(a2m, bh, acc2[nt]);
            acc2[nt] = MFMA16(a2h, bm, acc2[nt]);
            acc2[nt] = MFMA16(a2h, bh, acc2[nt]);
        }
    }
#pragma unroll
    for (int nt = 0; nt < 4; nt++) {
        int col = (ngb + nt) * 16 + lm;
        float b2 = gb2[g * DH + col];
#pragma unroll
        for (int r = 0; r < 4; r++) {
            int row = mt * 16 + quad * 4 + r;
            g_enc[((size_t)(n0 + row) * G + g) * DH + col] = acc2[nt][r] + b2;
        }
    }
}

// ---------------- fused encoder launch: rh(128) + sf(128) + genc(1024) blocks ----------------
__global__ __launch_bounds__(256) void k_enc_all(
        const float* __restrict__ hL, const float* __restrict__ feat,
        const float* __restrict__ sf_g, const float* __restrict__ sf_b,
        const float* __restrict__ gln_g, const float* __restrict__ gln_b,
        const short* Brh1H, const short* Brh1M, const short* Brh1L, const float* rh_b1,
        const short* Brh2H, const short* Brh2M, const short* Brh2L, const float* rh_b2,
        const short* Bsf1H, const short* Bsf1M, const short* Bsf1L, const float* sf_b1,
        const short* Bsf2H, const short* Bsf2M, const short* Bsf2L, const float* sf_b2,
        const short* Bgf1H, const short* Bgf1M, const short* Bgf1L, const float* gf_b1,
        const short* Bgf2H, const short* Bgf2M, const short* Bgf2L, const float* gf_b2,
        float* __restrict__ h_enc, float* __restrict__ s_enc, float* __restrict__ g_enc) {
    __shared__ __align__(16) char smem[3 * 8448];   // 25.3 KB -> 6 blocks/CU
    int bid = blockIdx.x;
    if (bid < 128)
        enc2_body<16, false>(bid, smem, hL, nullptr, nullptr,
                             Brh1H, Brh1M, Brh1L, rh_b1, Brh2H, Brh2M, Brh2L, rh_b2, h_enc);
    else if (bid < 256)
        enc2_body<4, true>(bid - 128, smem, feat, sf_g, sf_b,
                           Bsf1H, Bsf1M, Bsf1L, sf_b1, Bsf2H, Bsf2M, Bsf2L, sf_b2, s_enc);
    else {
        int idx = bid - 256;    // (idx & 7) = group -> XCD affinity for gf weights
        genc_one(idx >> 3, idx & 7, smem, feat, gln_g, gln_b,
                 Bgf1H, Bgf1M, Bgf1L, gf_b1, Bgf2H, Bgf2M, Bgf2L, gf_b2, g_enc);
    }
}

// ---- router staging helper: split3 16 fp32 values -> 6 bf16x8 LDS fragment writes ----
__device__ __forceinline__ void stage16v(float4 a, float4 b, float4 c, float4 d,
                                         char* smem, int wo0, int wo1) {
    float v0[8] = {a.x, a.y, a.z, a.w, b.x, b.y, b.z, b.w};
    float v1[8] = {c.x, c.y, c.z, c.w, d.x, d.y, d.z, d.w};
    bf16x8 h0, m0, l0, h1, m1, l1;
#pragma unroll
    for (int j = 0; j < 8; j++) { short hh, mm, ll; split3(v0[j], hh, mm, ll); h0[j]=hh; m0[j]=mm; l0[j]=ll; }
#pragma unroll
    for (int j = 0; j < 8; j++) { short hh, mm, ll; split3(v1[j], hh, mm, ll); h1[j]=hh; m1[j]=mm; l1[j]=ll; }
    *(bf16x8*)(smem + wo0) = h0;           *(bf16x8*)(smem + wo1) = h1;
    *(bf16x8*)(smem + 16384 + wo0) = m0;   *(bf16x8*)(smem + 16384 + wo1) = m1;
    *(bf16x8*)(smem + 32768 + wo0) = l0;   *(bf16x8*)(smem + 32768 + wo1) = l1;
}

// ---------------- MFMA router v8: 64 tokens x 1 group, coalesced fp32 staging + T14 prefetch ----------------
// Round-0 data flow (fp32 h/s/g_enc = byte-minimal exact sources) with two fixes:
//   (1) staging loads are coalesced: thread = (row tid>>3, 16-col block tid&7) -> 64B contiguous;
//   (2) next chunk's 64B load is register-prefetched at the top of the current compute region
//       (straight-line, all indices compile-time) -> barrier drains are free.
// Chunk 3 (h*g): g reconstructed BIT-EXACTLY from this thread's own LDS splits (resident from
// chunk 2); h from a register prefetch issued during chunk-2 compute. Zero extra streams.
__global__ __launch_bounds__(512) void k_router_mfma(
        const float* __restrict__ h_enc, const float* __restrict__ s_enc,
        const float* __restrict__ g_enc,
        const short* __restrict__ BpgH, const short* __restrict__ BpgM, const short* __restrict__ BpgL,
        const short* __restrict__ BirH, const short* __restrict__ BirM, const short* __restrict__ BirL,
        const float* __restrict__ pb1, const float* __restrict__ pw2, const float* __restrict__ pb2,
        const float* __restrict__ ib1, const float* __restrict__ iw2, const float* __restrict__ ib2,
        float* __restrict__ glog, float* __restrict__ ilog) {
    const int g = blockIdx.x & 7;       // group -> XCD affinity for B + g_enc
    const int bx = blockIdx.x >> 3;     // 64-token tile (0..63)
    const int n0 = bx * 64;
    const int tid = threadIdx.x;
    const int wave = tid >> 6, lane = tid & 63;
    const int quad = lane >> 4, lm = lane & 15;
    const bool is_pg = wave < 4;
    const int nbase = (wave & 3) * 2;   // 2 n-tiles per wave, 4 waves cover 8
    const short* Bh = is_pg ? BpgH : (BirH + (size_t)g * 65536);
    const short* Bm = is_pg ? BpgM : (BirM + (size_t)g * 65536);
    const short* Bl = is_pg ? BpgL : (BirL + (size_t)g * 65536);

    // LDS: A staging for one 4-kb chunk: [split 3][kbl 4][t16 4][lane 64][8 shorts] = 48 KB.
    // Epilogue (2 x 32x129 fp32 = 33 KB) aliases it after the K-loop.
    __shared__ __align__(16) char smem[49152];

    // coalesced staging map: thread -> (token row sr, 16-col block scb); 64B contiguous per thread
    const int sr = tid >> 3, scb = tid & 7;
    const float* hrow = h_enc + (size_t)(n0 + sr) * DH + scb * 16;
    const float* srow = s_enc + (size_t)(n0 + sr) * DH + scb * 16;
    const float* grow = g_enc + ((size_t)(n0 + sr) * G + g) * DH + scb * 16;
    // LDS fragment offsets for this thread's 16 values (two quads of 8):
    const int skbl = scb >> 1, st16 = sr >> 4, slm = sr & 15, sq0 = (scb & 1) * 2;
    const int wo0 = skbl * 4096 + st16 * 1024 + (sq0 * 16 + slm) * 16;
    const int wo1 = wo0 + 256;   // next quad = +16 lanes * 16B

    f32x4 acc[4][2];
#pragma unroll
    for (int mt = 0; mt < 4; mt++)
#pragma unroll
        for (int nt = 0; nt < 2; nt++) acc[mt][nt] = (f32x4)(0.f);

    float4 A0, A1, A2, A3;   // staging prefetch regs (16 VGPR)

#define LOAD4(P) { const float4* p4_ = (const float4*)(P); \
                   A0 = p4_[0]; A1 = p4_[1]; A2 = p4_[2]; A3 = p4_[3]; }
#define COMPUTE_CHUNK(CH) { _Pragma("unroll") \
    for (int kbl = 0; kbl < 4; kbl++) { \
        const int kb = (CH) * 4 + kbl; \
        bf16x8 Ahf[4], Amf[4], Alf[4]; \
        _Pragma("unroll") \
        for (int mt = 0; mt < 4; mt++) { \
            size_t loff = (size_t)kbl * 4096 + mt * 1024 + (size_t)lane * 16; \
            Ahf[mt] = *(const bf16x8*)(smem + loff); \
            Amf[mt] = *(const bf16x8*)(smem + 16384 + loff); \
            Alf[mt] = *(const bf16x8*)(smem + 32768 + loff); \
        } \
        _Pragma("unroll") \
        for (int nt = 0; nt < 2; nt++) { \
            size_t bi = (((size_t)kb * 8 + nbase + nt) * 64 + lane) * 8; \
            bf16x8 bh = *(const bf16x8*)&Bh[bi]; \
            bf16x8 bm = *(const bf16x8*)&Bm[bi]; \
            bf16x8 bl = *(const bf16x8*)&Bl[bi]; \
            _Pragma("unroll") \
            for (int mt = 0; mt < 4; mt++) { \
                acc[mt][nt] = MFMA16(Alf[mt], bh, acc[mt][nt]); \
                acc[mt][nt] = MFMA16(Amf[mt], bm, acc[mt][nt]); \
                acc[mt][nt] = MFMA16(Ahf[mt], bl, acc[mt][nt]); \
                acc[mt][nt] = MFMA16(Amf[mt], bh, acc[mt][nt]); \
                acc[mt][nt] = MFMA16(Ahf[mt], bm, acc[mt][nt]); \
                acc[mt][nt] = MFMA16(Ahf[mt], bh, acc[mt][nt]); \
            } \
        } \
    } }

    // ---------------- chunk 0 (h_enc cols 0..127) ----------------
    LOAD4(hrow);
    stage16v(A0, A1, A2, A3, smem, wo0, wo1);
    __syncthreads();
    LOAD4(srow);                 // prefetch chunk 1; completes during chunk-0 MFMAs
    COMPUTE_CHUNK(0);

    // ---------------- chunk 1 (s_enc) ----------------
    __syncthreads();
    stage16v(A0, A1, A2, A3, smem, wo0, wo1);
    __syncthreads();
    LOAD4(grow);                 // prefetch chunk 2
    COMPUTE_CHUNK(1);

    // ---------------- chunk 2 (g_enc) ----------------
    __syncthreads();
    stage16v(A0, A1, A2, A3, smem, wo0, wo1);
    __syncthreads();
    float4 H0, H1, H2, H3;       // prefetch h again for the h*g chunk (L2/L3-hot)
    { const float4* p4_ = (const float4*)hrow; H0 = p4_[0]; H1 = p4_[1]; H2 = p4_[2]; H3 = p4_[3]; }
    COMPUTE_CHUNK(2);

    // ---------------- chunk 3 (h*g): g from own LDS splits (bit-exact), h from regs ----------------
    __syncthreads();             // chunk-2 fragment reads complete before own-slot rewrite
    {
        bf16x8 gh0 = *(const bf16x8*)(smem + wo0),          gh1 = *(const bf16x8*)(smem + wo1);
        bf16x8 gm0 = *(const bf16x8*)(smem + 16384 + wo0),  gm1 = *(const bf16x8*)(smem + 16384 + wo1);
        bf16x8 gl0 = *(const bf16x8*)(smem + 32768 + wo0),  gl1 = *(const bf16x8*)(smem + 32768 + wo1);
        float gv[16];
#pragma unroll
        for (int j = 0; j < 8; j++) gv[j]     = bf2f(gh0[j]) + bf2f(gm0[j]) + bf2f(gl0[j]);
#pragma unroll
        for (int j = 0; j < 8; j++) gv[8 + j] = bf2f(gh1[j]) + bf2f(gm1[j]) + bf2f(gl1[j]);
        float4 P0 = make_float4(H0.x * gv[0],  H0.y * gv[1],  H0.z * gv[2],  H0.w * gv[3]);
        float4 P1 = make_float4(H1.x * gv[4],  H1.y * gv[5],  H1.z * gv[6],  H1.w * gv[7]);
        float4 P2 = make_float4(H2.x * gv[8],  H2.y * gv[9],  H2.z * gv[10], H2.w * gv[11]);
        float4 P3 = make_float4(H3.x * gv[12], H3.y * gv[13], H3.z * gv[14], H3.w * gv[15]);
        stage16v(P0, P1, P2, P3, smem, wo0, wo1);
    }
    __syncthreads();
    COMPUTE_CHUNK(3);

#undef LOAD4
#undef COMPUTE_CHUNK

    // epilogue: two 32-row halves reusing staging LDS (ph 32x129 + ih 32x129 = 33 KB)
    float (*ph)[129] = (float(*)[129])smem;
    float (*ih)[129] = (float(*)[129])(smem + 32 * 129 * 4);
    for (int h = 0; h < 2; h++) {
        __syncthreads();   // h=0: K-loop LDS reads done; h=1: prev half's logit reads done
#pragma unroll
        for (int mi = 0; mi < 2; mi++) {
            int mt = 2 * h + mi;
#pragma unroll
            for (int nt = 0; nt < 2; nt++) {
                int col = (nbase + nt) * 16 + lm;
                float b1 = is_pg ? pb1[col] : ib1[g * DH + col];
                float* dst = is_pg ? &ph[0][0] : &ih[0][0];
#pragma unroll
                for (int r = 0; r < 4; r++) {
                    int row = mi * 16 + quad * 4 + r;
                    dst[row * 129 + col] = gelu_t(acc[mt][nt][r] + b1);
                }
            }
        }
        __syncthreads();
        if (tid < 128) {
            // glog dot: 4 lanes per token, 32 i's each, pair-reduce
            int t = tid >> 2, q = tid & 3;
            float s = 0.f;
            for (int i = q * 32; i < q * 32 + 32; i++) s += ph[t][i] * pw2[i];
            s += __shfl_xor(s, 1);
            s += __shfl_xor(s, 2);
            if (q == 0) glog[(size_t)(n0 + h * 32 + t) * G + g] = s + pb2[0]; // TEMP = 1.0
        } else if (tid < 384) {
            // ilog dot: 2 lanes per (token, e), 64 i's each
            int t2 = tid - 128;
            int t = t2 >> 3, e = (t2 >> 1) & 3, half = t2 & 1;
            const float* wv = iw2 + (size_t)g * DH * ES;
            float s = 0.f;
            for (int i = half * 64; i < half * 64 + 64; i++) s += ih[t][i] * wv[i * ES + e];
            s += __shfl_xor(s, 1);
            if (half == 0) ilog[((size_t)(n0 + h * 32 + t) * G + g) * ES + e] = s + ib2[g * ES + e];
        }
    }
}

// ---------------- top-k softmax + dispatch to per-expert lists ----------------
__global__ void k_topk(const float* __restrict__ glog, const float* __restrict__ ilog,
                       int* __restrict__ cnt, int* __restrict__ toks, float* __restrict__ wgts) {
    int n = blockIdx.x * blockDim.x + threadIdx.x;
    if (n >= N_TOK) return;
    float gl[G];
#pragma unroll
    for (int g = 0; g < G; g++) gl[g] = glog[(size_t)n * G + g];
    int i1 = 0; float v1 = gl[0];
#pragma unroll
    for (int g = 1; g < G; g++) if (gl[g] > v1) { v1 = gl[g]; i1 = g; }
    int i2 = -1; float v2 = -1e30f;
#pragma unroll
    for (int g = 0; g < G; g++) if (g != i1 && gl[g] > v2) { v2 = gl[g]; i2 = g; }
    float eg = expf(v2 - v1);
    float den = 1.0f / (1.0f + eg);
    float gw_sel[2] = { den, eg * den };
    int g_sel[2] = { i1, i2 };
#pragma unroll
    for (int s = 0; s < 2; s++) {
        int g = g_sel[s]; float gw = gw_sel[s];
        float il[ES];
#pragma unroll
        for (int e = 0; e < ES; e++) il[e] = ilog[((size_t)n * G + g) * ES + e];
        int j1 = 0; float u1 = il[0];
#pragma unroll
        for (int e = 1; e < ES; e++) if (il[e] > u1) { u1 = il[e]; j1 = e; }
        int j2 = -1; float u2 = -1e30f;
#pragma unroll
        for (int e = 0; e < ES; e++) if (e != j1 && il[e] > u2) { u2 = il[e]; j2 = e; }
        float ei = expf(u2 - u1);
        float d2 = 1.0f / (1.0f + ei);
        int ex1 = g * ES + j1, ex2 = g * ES + j2;
        int p1 = atomicAdd(&cnt[ex1], 1);
        toks[(size_t)ex1 * N_TOK + p1] = n * 4 + s * 2;     wgts[(size_t)ex1 * N_TOK + p1] = gw * d2;
        int p2 = atomicAdd(&cnt[ex2], 1);
        toks[(size_t)ex2 * N_TOK + p2] = n * 4 + s * 2 + 1; wgts[(size_t)ex2 * N_TOK + p2] = gw * ei * d2;
    }
}

// ---------------- sparse expert MLPs via bf16 MFMA; XCD-swizzled; es aliases hs (33KB LDS) ----------------
__global__ __launch_bounds__(512) void k_expert_mfma(
        const __hip_bfloat16* __restrict__ h_normb,
        const short* __restrict__ wB1, const float* __restrict__ eb1,
        const short* __restrict__ wB2, const float* __restrict__ eb2,
        const int* __restrict__ cnt, const int* __restrict__ toks,
        const float* __restrict__ wgts, float* __restrict__ part) {
    const int e = blockIdx.x & 31;
    const int slot = blockIdx.x >> 5;
    const int c = cnt[e];
    const int start = slot * BT;
    if (start >= c) return;
    const int m = min(BT, c - start);

    __shared__ short hs[BT][520];                   // 33.3 KB; es aliases (dead after phase 1)
    short (*es)[264] = (short(*)[264])&hs[0][0];    // 16.9 KB
    __shared__ int   tok_s[BT];
    __shared__ float w_s[BT];

    const int tid = threadIdx.x;
    if (tid < BT) {
        bool ok = tid < m;
        tok_s[tid] = ok ? toks[(size_t)e * N_TOK + start + tid] : 0;
        w_s[tid]   = ok ? wgts[(size_t)e * N_TOK + start + tid] : 0.f;
    }
    __syncthreads();
    for (int idx = tid; idx < BT * 64; idx += 512) {
        int t = idx >> 6, ch = idx & 63;
        uint4 v = make_uint4(0, 0, 0, 0);
        if (t < m) v = *((const uint4*)(h_normb + (size_t)(tok_s[t] >> 2) * DM) + ch);
        *(uint4*)&hs[t][ch * 8] = v;
    }
    __syncthreads();

    const int wave = tid >> 6, lane = tid & 63;
    const int quad = lane >> 4, lm = lane & 15;

    // ---- phase 1: acc = hs @ W1 (reads hs) ----
    const int ng = wave * 2;
    f32x4 acc1[2][2];
#pragma unroll
    for (int a = 0; a < 2; a++)
#pragma unroll
        for (int b = 0; b < 2; b++) acc1[a][b] = (f32x4)(0.f);
    {
        const short* w1e = wB1 + (size_t)e * DM * DE;
        for (int kb = 0; kb < 16; kb++) {
            bf16x8 a0 = *(const bf16x8*)&hs[lm][kb * 32 + quad * 8];
            bf16x8 a1 = *(const bf16x8*)&hs[16 + lm][kb * 32 + quad * 8];
            const short* wp = w1e + ((size_t)kb * 16 + ng) * 512 + lane * 8;
#pragma unroll
            for (int nt = 0; nt < 2; nt++) {
                bf16x8 b = *(const bf16x8*)(wp + nt * 512);
                acc1[0][nt] = MFMA16(a0, b, acc1[0][nt]);
                acc1[1][nt] = MFMA16(a1, b, acc1[1][nt]);
            }
        }
    }
    __syncthreads();   // all waves done reading hs before es overwrite
#pragma unroll
    for (int nt = 0; nt < 2; nt++) {
        int col = (ng + nt) * 16 + lm;
        float b1 = eb1[e * DE + col];
#pragma unroll
        for (int mt = 0; mt < 2; mt++)
#pragma unroll
        for (int r = 0; r < 4; r++) {
            int row = mt * 16 + quad * 4 + r;
            es[row][col] = f2bf(gelu_t(acc1[mt][nt][r] + b1));
        }
    }
    __syncthreads();

    // ---- phase 2: part[tok] = w * (es @ W2 + b2) ----
    {
        const int ng2 = wave * 4;
        f32x4 acc[2][4];
#pragma unroll
        for (int a = 0; a < 2; a++)
#pragma unroll
            for (int b = 0; b < 4; b++) acc[a][b] = (f32x4)(0.f);
        const short* w2e = wB2 + (size_t)e * DE * DM;
        for (int kb = 0; kb < 8; kb++) {
            bf16x8 a0 = *(const bf16x8*)&es[lm][kb * 32 + quad * 8];
            bf16x8 a1 = *(const bf16x8*)&es[16 + lm][kb * 32 + quad * 8];
            const short* wp = w2e + ((size_t)kb * 32 + ng2) * 512 + lane * 8;
#pragma unroll
            for (int nt = 0; nt < 4; nt++) {
                bf16x8 b = *(const bf16x8*)(wp + nt * 512);
                acc[0][nt] = MFMA16(a0, b, acc[0][nt]);
                acc[1][nt] = MFMA16(a1, b, acc[1][nt]);
            }
        }
        const float* b2 = eb2 + (size_t)e * DM;
#pragma unroll
        for (int mt = 0; mt < 2; mt++)
#pragma unroll
        for (int r = 0; r < 4; r++) {
            int row = mt * 16 + quad * 4 + r;
            if (row < m) {
                float w = w_s[row];
                float* prow = part + (size_t)tok_s[row] * DM;
#pragma unroll
                for (int nt = 0; nt < 4; nt++) {
                    int col = (ng2 + nt) * 16 + lm;
                    prow[col] = w * (acc[mt][nt][r] + b2[col]);
                }
            }
        }
    }
}

// ---------------- final reduce: out[n] = sum_s part[n*4+s] ----------------
__global__ void k_reduce(const float* __restrict__ part, float* __restrict__ out) {
    int n = blockIdx.x;
    int j = threadIdx.x; // 0..127
    const float4* p = (const float4*)(part + (size_t)n * 4 * DM);
    float4 a = p[j], b = p[128 + j], c = p[256 + j], d = p[384 + j];
    float4 r = make_float4(a.x + b.x + c.x + d.x, a.y + b.y + c.y + d.y,
                           a.z + b.z + c.z + d.z, a.w + b.w + c.w + d.w);
    ((float4*)(out + (size_t)n * DM))[j] = r;
}

extern "C" void kernel_launch(void* const* d_in, const int* in_sizes, int n_in,
                              void* d_out, int out_size, void* d_ws, size_t ws_size,
                              hipStream_t stream) {
    const float* hidden  = (const float*)d_in[0];
    const float* feat    = (const float*)d_in[1];
    const float* pre_g   = (const float*)d_in[2];
    const float* pre_b   = (const float*)d_in[3];
    const float* rh_g    = (const float*)d_in[4];
    const float* rh_b    = (const float*)d_in[5];
    const float* rh_w1   = (const float*)d_in[6];
    const float* rh_b1   = (const float*)d_in[7];
    const float* rh_w2   = (const float*)d_in[8];
    const float* rh_b2   = (const float*)d_in[9];
    const float* sf_g    = (const float*)d_in[10];
    const float* sf_b    = (const float*)d_in[11];
    const float* sf_w1   = (const float*)d_in[12];
    const float* sf_b1   = (const float*)d_in[13];
    const float* sf_w2   = (const float*)d_in[14];
    const float* sf_b2   = (const float*)d_in[15];
    const float* gln_g   = (const float*)d_in[16];
    const float* gln_b   = (const float*)d_in[17];
    const float* gf_w1   = (const float*)d_in[18];
    const float* gf_b1   = (const float*)d_in[19];
    const float* gf_w2   = (const float*)d_in[20];
    const float* gf_b2   = (const float*)d_in[21];
    const float* pgs_w1  = (const float*)d_in[22];
    const float* pgs_b1  = (const float*)d_in[23];
    const float* pgs_w2  = (const float*)d_in[24];
    const float* pgs_b2  = (const float*)d_in[25];
    const float* ir_w1   = (const float*)d_in[26];
    const float* ir_b1   = (const float*)d_in[27];
    const float* ir_w2   = (const float*)d_in[28];
    const float* ir_b2   = (const float*)d_in[29];
    const float* ex_w1   = (const float*)d_in[30];
    const float* ex_b1   = (const float*)d_in[31];
    const float* ex_w2   = (const float*)d_in[32];
    const float* ex_b2   = (const float*)d_in[33];
    float* out = (float*)d_out;

    // workspace carving (256B-aligned)
    char* w = (char*)d_ws;
    auto alloc = [&](size_t bytes) { void* r = (void*)w; w += (bytes + 255) & ~(size_t)255; return r; };
    __hip_bfloat16* h_normb = (__hip_bfloat16*)alloc((size_t)N_TOK * DM * 2);
    float* h_enc = (float*)alloc((size_t)N_TOK * DH * 4);
    float* s_enc = (float*)alloc((size_t)N_TOK * DH * 4);
    float* g_enc = (float*)alloc((size_t)N_TOK * G * DH * 4);
    float* glog  = (float*)alloc((size_t)N_TOK * G * 4);
    float* ilog  = (float*)alloc((size_t)N_TOK * G * ES * 4);
    float* wgts  = (float*)alloc((size_t)E_EXP * N_TOK * 4);
    short* wB1   = (short*)alloc((size_t)E_EXP * DM * DE * 2);
    short* wB2   = (short*)alloc((size_t)E_EXP * DE * DM * 2);
    short* BpgH  = (short*)alloc((size_t)16 * 8 * 512 * 2);
    short* BpgM  = (short*)alloc((size_t)16 * 8 * 512 * 2);
    short* BpgL  = (short*)alloc((size_t)16 * 8 * 512 * 2);
    short* BirH  = (short*)alloc((size_t)G * 16 * 8 * 512 * 2);
    short* BirM  = (short*)alloc((size_t)G * 16 * 8 * 512 * 2);
    short* BirL  = (short*)alloc((size_t)G * 16 * 8 * 512 * 2);
    short* Brh1H = (short*)alloc((size_t)16 * 8 * 512 * 2);
    short* Brh1M = (short*)alloc((size_t)16 * 8 * 512 * 2);
    short* Brh1L = (short*)alloc((size_t)16 * 8 * 512 * 2);
    short* Brh2H = (short*)alloc((size_t)4 * 8 * 512 * 2);
    short* Brh2M = (short*)alloc((size_t)4 * 8 * 512 * 2);
    short* Brh2L = (short*)alloc((size_t)4 * 8 * 512 * 2);
    short* Bsf1H = (short*)alloc((size_t)4 * 8 * 512 * 2);
    short* Bsf1M = (short*)alloc((size_t)4 * 8 * 512 * 2);
    short* Bsf1L = (short*)alloc((size_t)4 * 8 * 512 * 2);
    short* Bsf2H = (short*)alloc((size_t)4 * 8 * 512 * 2);
    short* Bsf2M = (short*)alloc((size_t)4 * 8 * 512 * 2);
    short* Bsf2L = (short*)alloc((size_t)4 * 8 * 512 * 2);
    short* Bgf1H = (short*)alloc((size_t)G * 1 * 8 * 512 * 2);
    short* Bgf1M = (short*)alloc((size_t)G * 1 * 8 * 512 * 2);
    short* Bgf1L = (short*)alloc((size_t)G * 1 * 8 * 512 * 2);
    short* Bgf2H = (short*)alloc((size_t)G * 4 * 8 * 512 * 2);
    short* Bgf2M = (short*)alloc((size_t)G * 4 * 8 * 512 * 2);
    short* Bgf2L = (short*)alloc((size_t)G * 4 * 8 * 512 * 2);
    int* cnt     = (int*)alloc(E_EXP * 4);
    int* toks    = (int*)alloc((size_t)E_EXP * N_TOK * 4);
    // union region (disjoint live ranges, stream-ordered):
    //   hL   [k_pre -> k_enc_all]          8.4 MB
    //   part [k_expert_mfma -> k_reduce]  33.6 MB
    char* uni   = (char*)alloc((size_t)N_TOK * 4 * DM * 4); // 33.6 MB = max
    float* hL   = (float*)uni;
    float* part = (float*)uni;

    hipMemsetAsync(cnt, 0, E_EXP * sizeof(int), stream);

    // fused pre-pass: 10 weight-conversion jobs + 4096 LN blocks, one launch
    ConvJobs J;
    int b0 = 0;
    auto mkjob = [&](int i, const float* s, short* dh, short* dm, short* dl,
                     int KB, int NB, int Kreal, int plain, int nmat) {
        J.j[i] = ConvJob{s, dh, dm, dl, KB, NB, Kreal, plain, b0};
        b0 += KB * nmat;
    };
    mkjob(0, ex_w1, wB1, nullptr, nullptr, 16, 16, 512, 1, E_EXP);
    mkjob(1, ex_w2, wB2, nullptr, nullptr, 8, 32, 256, 1, E_EXP);
    mkjob(2, pgs_w1, BpgH, BpgM, BpgL, 16, 8, 512, 0, 1);
    mkjob(3, ir_w1, BirH, BirM, BirL, 16, 8, 512, 0, G);
    mkjob(4, rh_w1, Brh1H, Brh1M, Brh1L, 16, 8, 512, 0, 1);
    mkjob(5, rh_w2, Brh2H, Brh2M, Brh2L, 4, 8, 128, 0, 1);
    mkjob(6, sf_w1, Bsf1H, Bsf1M, Bsf1L, 4, 8, 128, 0, 1);
    mkjob(7, sf_w2, Bsf2H, Bsf2M, Bsf2L, 4, 8, 128, 0, 1);
    mkjob(8, gf_w1, Bgf1H, Bgf1M, Bgf1L, 1, 8, 16, 0, G);
    mkjob(9, gf_w2, Bgf2H, Bgf2M, Bgf2L, 4, 8, 128, 0, G);
    k_pre<<<b0 + N_TOK, 256, 0, stream>>>(J, b0, hidden, pre_g, pre_b, rh_g, rh_b, h_normb, hL);

    // fused encoders: rh(128) + sf(128) + per-(tile,group) genc(1024) = 1280 blocks
    k_enc_all<<<256 + (N_TOK / 32) * G, 256, 0, stream>>>(
        hL, feat, sf_g, sf_b, gln_g, gln_b,
        Brh1H, Brh1M, Brh1L, rh_b1, Brh2H, Brh2M, Brh2L, rh_b2,
        Bsf1H, Bsf1M, Bsf1L, sf_b1, Bsf2H, Bsf2M, Bsf2L, sf_b2,
        Bgf1H, Bgf1M, Bgf1L, gf_b1, Bgf2H, Bgf2M, Bgf2L, gf_b2,
        h_enc, s_enc, g_enc);

    // router v8: 64-token tiles, 512 threads, coalesced fp32 staging + reg prefetch
    k_router_mfma<<<(N_TOK / 64) * G, 512, 0, stream>>>(h_enc, s_enc, g_enc,
                                             BpgH, BpgM, BpgL, BirH, BirM, BirL,
                                             pgs_b1, pgs_w2, pgs_b2, ir_b1, ir_w2, ir_b2,
                                             glog, ilog);

    k_topk<<<N_TOK / 256, 256, 0, stream>>>(glog, ilog, cnt, toks, wgts);
    // XCD-swizzled 1D expert grid: bid = slot*32 + e
    k_expert_mfma<<<(N_TOK / BT) * E_EXP, 512, 0, stream>>>(h_normb, wB1, ex_b1, wB2, ex_b2,
                                                            cnt, toks, wgts, part);
    k_reduce<<<N_TOK, 128, 0, stream>>>(part, out);
}